// Round 1
// baseline (231.894 us; speedup 1.0000x reference)
//
#include <hip/hip_runtime.h>
#include <hip/hip_bf16.h>

#define B_ 8
#define C_ 256
#define N_ 4096
#define HID_ 512

typedef __bf16 bf16;
typedef bf16 bf16x8 __attribute__((ext_vector_type(8)));
typedef bf16 bf16x4 __attribute__((ext_vector_type(4)));
typedef float f32x4 __attribute__((ext_vector_type(4)));

// ws layout (bytes)
#define T_OFF    0u           // t bf16 [B*N][256]            16 MB
#define U_OFF    16777216u    // U f32  [B][8][64][64]         1 MB
#define S_OFF    17825792u    // S f32  [B][8][64]            16 KB
#define NS_OFF   17842176u    // nscale f32 [B*N]            128 KB
#define M2T_OFF  17973248u    // M2T bf16 [B][256][512]        2 MB
#define WQ_OFF   20070400u    // Wq bf16 [512][256]          256 KB
#define WK_OFF   20332544u
#define WV_OFF   20594688u

__device__ __forceinline__ f32x4 mfma16(bf16x8 a, bf16x8 b, f32x4 c) {
    return __builtin_amdgcn_mfma_f32_16x16x32_bf16(a, b, c, 0, 0, 0);
}

// ---- convert 3 weight matrices fp32 -> bf16 ----
__global__ void __launch_bounds__(256) k_cvtw(const float* __restrict__ wq,
                                              const float* __restrict__ wk,
                                              const float* __restrict__ wv,
                                              bf16* __restrict__ oq,
                                              bf16* __restrict__ ok,
                                              bf16* __restrict__ ov) {
    int m = blockIdx.x >> 6;
    const float* src = (m == 0) ? wq : ((m == 1) ? wk : wv);
    bf16* dst = (m == 0) ? oq : ((m == 1) ? ok : ov);
    int i0 = ((blockIdx.x & 63) * 256 + threadIdx.x) * 8;
    f32x4 a = *(const f32x4*)(src + i0);
    f32x4 b = *(const f32x4*)(src + i0 + 4);
    bf16x8 o;
#pragma unroll
    for (int j = 0; j < 4; ++j) { o[j] = (bf16)a[j]; o[j + 4] = (bf16)b[j]; }
    *(bf16x8*)(dst + i0) = o;
}

// ---- rmsnorm scale + write t = xn (bf16, [row=pixel][c]) ----
__global__ void __launch_bounds__(256) k_norm(const float* __restrict__ x,
                                              const float* __restrict__ gnorm,
                                              float* __restrict__ nscale,
                                              bf16* __restrict__ t) {
    int b = blockIdx.x >> 4;
    int pix = ((blockIdx.x & 15) << 8) + threadIdx.x;
    const float* xb = x + (size_t)b * C_ * N_ + pix;
    float ss = 0.f;
#pragma unroll 8
    for (int c = 0; c < C_; ++c) { float v = xb[(size_t)c * N_]; ss += v * v; }
    float s = 16.0f / fmaxf(sqrtf(ss), 1e-12f);
    nscale[b * N_ + pix] = s;
    bf16* tb = t + ((size_t)(b * N_ + pix)) * C_;
    for (int c0 = 0; c0 < C_; c0 += 8) {
        bf16x8 pk;
#pragma unroll
        for (int j = 0; j < 8; ++j)
            pk[j] = (bf16)(xb[(size_t)(c0 + j) * N_] * s * gnorm[c0 + j]);
        *(bf16x8*)(tb + c0) = pk;
    }
}

// ---- fused KV projection + U = exp(K)^T V , S = colsum(exp(K)) ----
// grid: 512 = B*HEADS*8 splits; block 256 (4 waves). Each block: 512 rows (4 sub-chunks of 128).
__global__ void __launch_bounds__(256) k_kv(const bf16* __restrict__ t,
                                            const bf16* __restrict__ wkb,
                                            const bf16* __restrict__ wvb,
                                            float* __restrict__ U,
                                            float* __restrict__ S) {
    __shared__ __align__(16) bf16 ekT[64][136];  // [d][row in sub-chunk]
    __shared__ __align__(16) bf16 vT[64][136];   // [e][row]
    int sp = blockIdx.x & 7;
    int h = (blockIdx.x >> 3) & 7;
    int b = blockIdx.x >> 6;
    int w = threadIdx.x >> 6;
    int l = threadIdx.x & 63;
    int l15 = l & 15, g = l >> 4;

    // weight fragments held in registers: wave w covers 32 cols of [k(64)|v(64)]
    const bf16* wsel = (w < 2) ? wkb : wvb;
    int c0 = (w & 1) * 32;
    bf16x8 wf[2][8];
#pragma unroll
    for (int nf = 0; nf < 2; ++nf)
#pragma unroll
        for (int ks = 0; ks < 8; ++ks)
            wf[nf][ks] = *(const bf16x8*)(wsel + (size_t)(h * 64 + c0 + nf * 16 + l15) * 256 + ks * 32 + g * 8);

    const f32x4 fz = {0.f, 0.f, 0.f, 0.f};
    f32x4 uacc[4];
#pragma unroll
    for (int df = 0; df < 4; ++df) uacc[df] = fz;

    int rowbase = b * N_ + sp * 512;
    bool isk = (w < 2);

    for (int sc = 0; sc < 4; ++sc) {
        int r0 = rowbase + sc * 128;
        f32x4 acc[8][2];
#pragma unroll
        for (int mf = 0; mf < 8; ++mf) { acc[mf][0] = fz; acc[mf][1] = fz; }
#pragma unroll
        for (int ks = 0; ks < 8; ++ks) {
#pragma unroll
            for (int mf = 0; mf < 8; ++mf) {
                bf16x8 a = *(const bf16x8*)(t + (size_t)(r0 + mf * 16 + l15) * 256 + ks * 32 + g * 8);
                acc[mf][0] = mfma16(a, wf[0][ks], acc[mf][0]);
                acc[mf][1] = mfma16(a, wf[1][ks], acc[mf][1]);
            }
        }
        __syncthreads();  // prior stage-2 reads done before overwrite
#pragma unroll
        for (int mf = 0; mf < 8; ++mf)
#pragma unroll
            for (int nf = 0; nf < 2; ++nf) {
                int cc = c0 + nf * 16 + l15;
                int rr = mf * 16 + g * 4;
                bf16x4 pk;
#pragma unroll
                for (int r = 0; r < 4; ++r) {
                    float v = acc[mf][nf][r];
                    pk[r] = (bf16)(isk ? __expf(v) : v);
                }
                if (isk) *(bf16x4*)(&ekT[cc][rr]) = pk;
                else     *(bf16x4*)(&vT[cc][rr]) = pk;
            }
        __syncthreads();
        // stage-2: U[d][e0..e0+15] partial over 128 rows; e0 = w*16
#pragma unroll
        for (int k2 = 0; k2 < 4; ++k2) {
            bf16x8 bv = *(const bf16x8*)(&vT[w * 16 + l15][k2 * 32 + g * 8]);
#pragma unroll
            for (int df = 0; df < 4; ++df) {
                bf16x8 ae = *(const bf16x8*)(&ekT[df * 16 + l15][k2 * 32 + g * 8]);
                uacc[df] = mfma16(ae, bv, uacc[df]);
            }
        }
        // S partial (from the same bf16 exp(k) values for consistency)
        {
            int d = threadIdx.x & 63;
            int q = threadIdx.x >> 6;
            float sum = 0.f;
#pragma unroll
            for (int i = 0; i < 32; ++i) sum += (float)ekT[d][q * 32 + i];
            atomicAdd(S + ((b * 8 + h) * 64 + d), sum);
        }
    }
    float* Ubh = U + ((size_t)(b * 8 + h)) * 4096;
#pragma unroll
    for (int df = 0; df < 4; ++df)
#pragma unroll
        for (int r = 0; r < 4; ++r)
            atomicAdd(Ubh + (df * 16 + g * 4 + r) * 64 + w * 16 + l15, uacc[df][r]);
}

// ---- attn = U/S ; M2T[b][o][h*64+d] = sum_e attn[d][e] * conv_w[o][h*64+e] ----
__global__ void __launch_bounds__(256) k_attn_m2(const float* __restrict__ U,
                                                 const float* __restrict__ S,
                                                 const float* __restrict__ cw,
                                                 bf16* __restrict__ m2t) {
    __shared__ float at[64][64];
    __shared__ float sl[64];
    int h = blockIdx.x & 7, b = blockIdx.x >> 3;
    int tid = threadIdx.x;
    if (tid < 64) sl[tid] = S[(b * 8 + h) * 64 + tid];
    __syncthreads();
    const float* Ub = U + (size_t)(b * 8 + h) * 4096;
    for (int it = 0; it < 16; ++it) {
        int idx = it * 256 + tid;
        at[idx >> 6][idx & 63] = Ub[idx] / sl[idx >> 6];
    }
    __syncthreads();
    int o = tid;
    float cwr[64];
#pragma unroll
    for (int e = 0; e < 64; ++e) cwr[e] = cw[(size_t)o * 512 + h * 64 + e];
    bf16* dst = m2t + (size_t)(b * 256 + o) * 512 + h * 64;
    for (int d0 = 0; d0 < 64; d0 += 8) {
        bf16x8 pk;
#pragma unroll
        for (int j = 0; j < 8; ++j) {
            float a2 = 0.f;
#pragma unroll
            for (int e = 0; e < 64; ++e) a2 += at[d0 + j][e] * cwr[e];
            pk[j] = (bf16)a2;
        }
        *(bf16x8*)(dst + d0) = pk;
    }
}

// ---- fused: q GEMM + per-head softmax + (qsm @ M2T) + bias + rmsnorm + residual ----
// grid 512 = B * 64 row-tiles of 64; block 256 (4 waves)
__global__ void __launch_bounds__(256) k_qout(const bf16* __restrict__ t,
                                              const bf16* __restrict__ wqb,
                                              const bf16* __restrict__ m2t,
                                              const float* __restrict__ x,
                                              const float* __restrict__ nscale,
                                              const float* __restrict__ gnorm,
                                              const float* __restrict__ gffn,
                                              const float* __restrict__ cb,
                                              float* __restrict__ out) {
    __shared__ __align__(16) bf16 qsm[64][520];
    __shared__ float rowsum[4][64];
    int b = blockIdx.x >> 6;
    int row0 = (blockIdx.x & 63) << 6;
    int w = threadIdx.x >> 6, l = threadIdx.x & 63;
    int l15 = l & 15, g = l >> 4;
    const f32x4 fz = {0.f, 0.f, 0.f, 0.f};

    // phase 1: q = t @ WqT   (wave w: 64 rows x cols [w*128, w*128+128))
    f32x4 acc[4][8];
#pragma unroll
    for (int mf = 0; mf < 4; ++mf)
#pragma unroll
        for (int nf = 0; nf < 8; ++nf) acc[mf][nf] = fz;
    const bf16* tb = t + (size_t)(b * N_ + row0) * 256;
#pragma unroll
    for (int ks = 0; ks < 8; ++ks) {
        bf16x8 bfr[8];
#pragma unroll
        for (int nf = 0; nf < 8; ++nf)
            bfr[nf] = *(const bf16x8*)(wqb + (size_t)(w * 128 + nf * 16 + l15) * 256 + ks * 32 + g * 8);
#pragma unroll
        for (int mf = 0; mf < 4; ++mf) {
            bf16x8 a = *(const bf16x8*)(tb + (size_t)(mf * 16 + l15) * 256 + ks * 32 + g * 8);
#pragma unroll
            for (int nf = 0; nf < 8; ++nf)
                acc[mf][nf] = mfma16(a, bfr[nf], acc[mf][nf]);
        }
    }
    // phase 2: per-head softmax over d (64 cols), * DH^-0.5, -> qsm LDS (bf16)
#pragma unroll
    for (int mf = 0; mf < 4; ++mf)
#pragma unroll
        for (int hh = 0; hh < 2; ++hh)
#pragma unroll
            for (int r = 0; r < 4; ++r) {
                float mx = -1e30f;
#pragma unroll
                for (int n2 = 0; n2 < 4; ++n2) mx = fmaxf(mx, acc[mf][hh * 4 + n2][r]);
                mx = fmaxf(mx, __shfl_xor(mx, 1));
                mx = fmaxf(mx, __shfl_xor(mx, 2));
                mx = fmaxf(mx, __shfl_xor(mx, 4));
                mx = fmaxf(mx, __shfl_xor(mx, 8));
                float p[4]; float sm = 0.f;
#pragma unroll
                for (int n2 = 0; n2 < 4; ++n2) { p[n2] = __expf(acc[mf][hh * 4 + n2][r] - mx); sm += p[n2]; }
                sm += __shfl_xor(sm, 1);
                sm += __shfl_xor(sm, 2);
                sm += __shfl_xor(sm, 4);
                sm += __shfl_xor(sm, 8);
                float scl = 0.125f / sm;
                int row = mf * 16 + g * 4 + r;
#pragma unroll
                for (int n2 = 0; n2 < 4; ++n2)
                    qsm[row][w * 128 + (hh * 4 + n2) * 16 + l15] = (bf16)(p[n2] * scl);
            }
    __syncthreads();
    // phase 3: out2 = qsm @ M2T  (wave w: 64 rows x cols [w*64, w*64+64) of 256)
    f32x4 acc2[4][4];
#pragma unroll
    for (int mf = 0; mf < 4; ++mf)
#pragma unroll
        for (int nf = 0; nf < 4; ++nf) acc2[mf][nf] = fz;
#pragma unroll
    for (int ks = 0; ks < 16; ++ks) {
        bf16x8 bm[4];
#pragma unroll
        for (int nf = 0; nf < 4; ++nf)
            bm[nf] = *(const bf16x8*)(m2t + (size_t)(b * 256 + w * 64 + nf * 16 + l15) * 512 + ks * 32 + g * 8);
#pragma unroll
        for (int mf = 0; mf < 4; ++mf) {
            bf16x8 a = *(const bf16x8*)(&qsm[mf * 16 + l15][ks * 32 + g * 8]);
#pragma unroll
            for (int nf = 0; nf < 4; ++nf)
                acc2[mf][nf] = mfma16(a, bm[nf], acc2[mf][nf]);
        }
    }
    // phase 4: +bias, rmsnorm over 256 cols, + xn residual, write [b][col][pix]
#pragma unroll
    for (int nf = 0; nf < 4; ++nf) {
        float bias = cb[w * 64 + nf * 16 + l15];
#pragma unroll
        for (int mf = 0; mf < 4; ++mf)
#pragma unroll
            for (int r = 0; r < 4; ++r) acc2[mf][nf][r] += bias;
    }
#pragma unroll
    for (int mf = 0; mf < 4; ++mf)
#pragma unroll
        for (int r = 0; r < 4; ++r) {
            float ssq = 0.f;
#pragma unroll
            for (int nf = 0; nf < 4; ++nf) ssq += acc2[mf][nf][r] * acc2[mf][nf][r];
            ssq += __shfl_xor(ssq, 1);
            ssq += __shfl_xor(ssq, 2);
            ssq += __shfl_xor(ssq, 4);
            ssq += __shfl_xor(ssq, 8);
            if (l15 == 0) rowsum[w][mf * 16 + g * 4 + r] = ssq;
        }
    __syncthreads();
#pragma unroll
    for (int mf = 0; mf < 4; ++mf) {
        int pixb = row0 + mf * 16 + g * 4;
        f32x4 ns4 = *(const f32x4*)(nscale + b * N_ + pixb);
        f32x4 scl4;
#pragma unroll
        for (int r = 0; r < 4; ++r) {
            int row = mf * 16 + g * 4 + r;
            float tot = rowsum[0][row] + rowsum[1][row] + rowsum[2][row] + rowsum[3][row];
            scl4[r] = 16.0f / fmaxf(sqrtf(tot), 1e-12f);
        }
#pragma unroll
        for (int nf = 0; nf < 4; ++nf) {
            int col = w * 64 + nf * 16 + l15;
            float gf = gffn[col], gn = gnorm[col];
            const float* xp = x + ((size_t)(b * 256 + col)) * N_ + pixb;
            f32x4 xv = *(const f32x4*)xp;
            f32x4 o4;
#pragma unroll
            for (int r = 0; r < 4; ++r)
                o4[r] = acc2[mf][nf][r] * scl4[r] * gf + xv[r] * ns4[r] * gn;
            *(f32x4*)(out + ((size_t)(b * 256 + col)) * N_ + pixb) = o4;
        }
    }
}

extern "C" void kernel_launch(void* const* d_in, const int* in_sizes, int n_in,
                              void* d_out, int out_size, void* d_ws, size_t ws_size,
                              hipStream_t stream) {
    const float* x     = (const float*)d_in[0];
    const float* Wq    = (const float*)d_in[1];
    const float* Wk    = (const float*)d_in[2];
    const float* Wv    = (const float*)d_in[3];
    const float* cw    = (const float*)d_in[4];
    const float* cb    = (const float*)d_in[5];
    const float* gffn  = (const float*)d_in[6];
    const float* gnorm = (const float*)d_in[7];
    char* ws = (char*)d_ws;
    bf16* t    = (bf16*)(ws + T_OFF);
    float* U   = (float*)(ws + U_OFF);
    float* S   = (float*)(ws + S_OFF);
    float* ns  = (float*)(ws + NS_OFF);
    bf16* m2t  = (bf16*)(ws + M2T_OFF);
    bf16* wqb  = (bf16*)(ws + WQ_OFF);
    bf16* wkb  = (bf16*)(ws + WK_OFF);
    bf16* wvb  = (bf16*)(ws + WV_OFF);
    float* out = (float*)d_out;

    hipMemsetAsync(U, 0, 1048576 + 16384, stream);  // U and S are contiguous
    k_cvtw<<<192, 256, 0, stream>>>(Wq, Wk, Wv, wqb, wkb, wvb);
    k_norm<<<128, 256, 0, stream>>>(x, gnorm, ns, t);
    k_kv<<<512, 256, 0, stream>>>(t, wkb, wvb, U, S);
    k_attn_m2<<<64, 256, 0, stream>>>(U, S, cw, m2t);
    k_qout<<<512, 256, 0, stream>>>(t, wqb, m2t, x, ns, gnorm, gffn, cb, out);
}

// Round 2
// 222.782 us; speedup vs baseline: 1.0409x; 1.0409x over previous
//
#include <hip/hip_runtime.h>
#include <hip/hip_bf16.h>

#define B_ 8
#define C_ 256
#define N_ 4096
#define HID_ 512

typedef __bf16 bf16;
typedef bf16 bf16x8 __attribute__((ext_vector_type(8)));
typedef bf16 bf16x4 __attribute__((ext_vector_type(4)));
typedef float f32x4 __attribute__((ext_vector_type(4)));

// ws layout (bytes)
#define T_OFF    0u           // t bf16 [B*N][256]            16 MB
#define U_OFF    16777216u    // U f32  [B][8][64][64]         1 MB
#define S_OFF    17825792u    // S f32  [B][8][64]            16 KB
#define NS_OFF   17842176u    // nscale f32 [B*N]            128 KB
#define M2T_OFF  17973248u    // M2T bf16 [B][256][512]        2 MB
#define WQ_OFF   20070400u    // Wq bf16 [512][256]          256 KB
#define WK_OFF   20332544u
#define WV_OFF   20594688u

__device__ __forceinline__ f32x4 mfma16(bf16x8 a, bf16x8 b, f32x4 c) {
    return __builtin_amdgcn_mfma_f32_16x16x32_bf16(a, b, c, 0, 0, 0);
}

// ---- convert 3 weight matrices fp32 -> bf16 ----
__global__ void __launch_bounds__(256) k_cvtw(const float* __restrict__ wq,
                                              const float* __restrict__ wk,
                                              const float* __restrict__ wv,
                                              bf16* __restrict__ oq,
                                              bf16* __restrict__ ok,
                                              bf16* __restrict__ ov) {
    int m = blockIdx.x >> 6;
    const float* src = (m == 0) ? wq : ((m == 1) ? wk : wv);
    bf16* dst = (m == 0) ? oq : ((m == 1) ? ok : ov);
    int i0 = ((blockIdx.x & 63) * 256 + threadIdx.x) * 8;
    f32x4 a = *(const f32x4*)(src + i0);
    f32x4 b = *(const f32x4*)(src + i0 + 4);
    bf16x8 o;
#pragma unroll
    for (int j = 0; j < 4; ++j) { o[j] = (bf16)a[j]; o[j + 4] = (bf16)b[j]; }
    *(bf16x8*)(dst + i0) = o;
}

// ---- rmsnorm scale + write t = xn (bf16, [row=pixel][c]) ----
// grid 512 = b(8) x chunk(64 of 64 pixels); block 256 = 4 waves; wave cq owns c-quarter.
// x values for this thread's quarter stay in registers for the t-write (single x pass).
__global__ void __launch_bounds__(256) k_norm(const float* __restrict__ x,
                                              const float* __restrict__ gnorm,
                                              float* __restrict__ nscale,
                                              bf16* __restrict__ t) {
    __shared__ float part[4][64];
    int b = blockIdx.x >> 6;
    int pix = ((blockIdx.x & 63) << 6) + (threadIdx.x & 63);
    int cq = threadIdx.x >> 6;
    const float* xb = x + (size_t)b * C_ * N_ + (size_t)(cq * 64) * N_ + pix;
    float xv[64];
    float ss = 0.f;
#pragma unroll 8
    for (int c = 0; c < 64; ++c) { xv[c] = xb[(size_t)c * N_]; ss += xv[c] * xv[c]; }
    part[cq][threadIdx.x & 63] = ss;
    __syncthreads();
    int p = threadIdx.x & 63;
    float tot = part[0][p] + part[1][p] + part[2][p] + part[3][p];
    float s = 16.0f / fmaxf(sqrtf(tot), 1e-12f);
    if (cq == 0) nscale[b * N_ + pix] = s;
    bf16* tb = t + ((size_t)(b * N_ + pix)) * C_ + cq * 64;
    for (int c0 = 0; c0 < 64; c0 += 8) {
        bf16x8 pk;
#pragma unroll
        for (int j = 0; j < 8; ++j)
            pk[j] = (bf16)(xv[c0 + j] * s * gnorm[cq * 64 + c0 + j]);
        *(bf16x8*)(tb + c0) = pk;
    }
}

// ---- fused KV projection + U = exp(K)^T V , S = colsum(exp(K)) ----
// grid: 1024 = B*HEADS*16 splits; block 256 (4 waves). Each block: 256 rows (2 sub-chunks of 128).
// Weight fragments re-read from L2 per ks (saves ~64 VGPR -> 4 waves/SIMD).
__global__ void __launch_bounds__(256, 4) k_kv(const bf16* __restrict__ t,
                                               const bf16* __restrict__ wkb,
                                               const bf16* __restrict__ wvb,
                                               float* __restrict__ U,
                                               float* __restrict__ S) {
    __shared__ __align__(16) bf16 ekT[64][136];  // [d][row in sub-chunk]
    __shared__ __align__(16) bf16 vT[64][136];   // [e][row]
    int sp = blockIdx.x & 15;
    int h = (blockIdx.x >> 4) & 7;
    int b = blockIdx.x >> 7;
    int w = threadIdx.x >> 6;
    int l = threadIdx.x & 63;
    int l15 = l & 15, g = l >> 4;

    const bf16* wsel = (w < 2) ? wkb : wvb;
    int c0 = (w & 1) * 32;
    const f32x4 fz = {0.f, 0.f, 0.f, 0.f};
    f32x4 uacc[4];
#pragma unroll
    for (int df = 0; df < 4; ++df) uacc[df] = fz;

    int rowbase = b * N_ + sp * 256;
    bool isk = (w < 2);

    for (int sc = 0; sc < 2; ++sc) {
        int r0 = rowbase + sc * 128;
        f32x4 acc[8][2];
#pragma unroll
        for (int mf = 0; mf < 8; ++mf) { acc[mf][0] = fz; acc[mf][1] = fz; }
#pragma unroll
        for (int ks = 0; ks < 8; ++ks) {
            bf16x8 w0 = *(const bf16x8*)(wsel + (size_t)(h * 64 + c0 + l15) * 256 + ks * 32 + g * 8);
            bf16x8 w1 = *(const bf16x8*)(wsel + (size_t)(h * 64 + c0 + 16 + l15) * 256 + ks * 32 + g * 8);
#pragma unroll
            for (int mf = 0; mf < 8; ++mf) {
                bf16x8 a = *(const bf16x8*)(t + (size_t)(r0 + mf * 16 + l15) * 256 + ks * 32 + g * 8);
                acc[mf][0] = mfma16(a, w0, acc[mf][0]);
                acc[mf][1] = mfma16(a, w1, acc[mf][1]);
            }
        }
        __syncthreads();  // prior stage-2 reads done before overwrite
#pragma unroll
        for (int mf = 0; mf < 8; ++mf)
#pragma unroll
            for (int nf = 0; nf < 2; ++nf) {
                int cc = c0 + nf * 16 + l15;
                int rr = mf * 16 + g * 4;
                bf16x4 pk;
#pragma unroll
                for (int r = 0; r < 4; ++r) {
                    float v = acc[mf][nf][r];
                    pk[r] = (bf16)(isk ? __expf(v) : v);
                }
                if (isk) *(bf16x4*)(&ekT[cc][rr]) = pk;
                else     *(bf16x4*)(&vT[cc][rr]) = pk;
            }
        __syncthreads();
        // stage-2: U[d][e0..e0+15] partial over 128 rows; e0 = w*16
#pragma unroll
        for (int k2 = 0; k2 < 4; ++k2) {
            bf16x8 bv = *(const bf16x8*)(&vT[w * 16 + l15][k2 * 32 + g * 8]);
#pragma unroll
            for (int df = 0; df < 4; ++df) {
                bf16x8 ae = *(const bf16x8*)(&ekT[df * 16 + l15][k2 * 32 + g * 8]);
                uacc[df] = mfma16(ae, bv, uacc[df]);
            }
        }
        // S partial (from the same bf16 exp(k) values for consistency)
        {
            int d = threadIdx.x & 63;
            int q = threadIdx.x >> 6;
            float sum = 0.f;
#pragma unroll
            for (int i = 0; i < 32; ++i) sum += (float)ekT[d][q * 32 + i];
            atomicAdd(S + ((b * 8 + h) * 64 + d), sum);
        }
    }
    float* Ubh = U + ((size_t)(b * 8 + h)) * 4096;
#pragma unroll
    for (int df = 0; df < 4; ++df)
#pragma unroll
        for (int r = 0; r < 4; ++r)
            atomicAdd(Ubh + (df * 16 + g * 4 + r) * 64 + w * 16 + l15, uacc[df][r]);
}

// ---- attn = U/S ; M2T[b][o][h*64+d] = sum_e attn[d][e] * conv_w[o][h*64+e] ----
// grid 256 = (b, h, d-quarter); block 256 (one thread per output channel o)
__global__ void __launch_bounds__(256) k_attn_m2(const float* __restrict__ U,
                                                 const float* __restrict__ S,
                                                 const float* __restrict__ cw,
                                                 bf16* __restrict__ m2t) {
    __shared__ float at[16][64];
    int dq = blockIdx.x & 3, h = (blockIdx.x >> 2) & 7, b = blockIdx.x >> 5;
    int tid = threadIdx.x;
    const float* Ub = U + (size_t)(b * 8 + h) * 4096 + dq * 16 * 64;
    const float* Sb = S + (b * 8 + h) * 64 + dq * 16;
    for (int it = 0; it < 4; ++it) {
        int idx = it * 256 + tid;  // 0..1023
        at[idx >> 6][idx & 63] = Ub[idx] / Sb[idx >> 6];
    }
    __syncthreads();
    int o = tid;
    float cwr[64];
#pragma unroll
    for (int e = 0; e < 64; ++e) cwr[e] = cw[(size_t)o * 512 + h * 64 + e];
    bf16* dst = m2t + (size_t)(b * 256 + o) * 512 + h * 64 + dq * 16;
    for (int j0 = 0; j0 < 16; j0 += 8) {
        bf16x8 pk;
#pragma unroll
        for (int j = 0; j < 8; ++j) {
            float a2 = 0.f;
#pragma unroll
            for (int e = 0; e < 64; ++e) a2 += at[j0 + j][e] * cwr[e];
            pk[j] = (bf16)a2;
        }
        *(bf16x8*)(dst + j0) = pk;
    }
}

// ---- fused: q GEMM + per-head softmax + (qsm @ M2T) + bias + rmsnorm + residual ----
// grid 1024 = B * 128 row-tiles of 32; block 256 (4 waves), 4 blocks/CU (LDS 33.8KB, VGPR<=128)
__global__ void __launch_bounds__(256, 4) k_qout(const bf16* __restrict__ t,
                                                 const bf16* __restrict__ wqb,
                                                 const bf16* __restrict__ m2t,
                                                 const float* __restrict__ x,
                                                 const float* __restrict__ nscale,
                                                 const float* __restrict__ gnorm,
                                                 const float* __restrict__ gffn,
                                                 const float* __restrict__ cb,
                                                 float* __restrict__ out) {
    __shared__ __align__(16) bf16 qsm[32][520];
    __shared__ float rowsum[4][32];
    int b = blockIdx.x >> 7;
    int row0 = (blockIdx.x & 127) << 5;
    int w = threadIdx.x >> 6, l = threadIdx.x & 63;
    int l15 = l & 15, g = l >> 4;
    const f32x4 fz = {0.f, 0.f, 0.f, 0.f};

    // phase 1: q = t @ WqT   (wave w: 32 rows x cols [w*128, w*128+128))
    f32x4 acc[2][8];
#pragma unroll
    for (int mf = 0; mf < 2; ++mf)
#pragma unroll
        for (int nf = 0; nf < 8; ++nf) acc[mf][nf] = fz;
    const bf16* tb = t + (size_t)(b * N_ + row0) * 256;
#pragma unroll
    for (int ks = 0; ks < 8; ++ks) {
        bf16x8 a0 = *(const bf16x8*)(tb + (size_t)(l15) * 256 + ks * 32 + g * 8);
        bf16x8 a1 = *(const bf16x8*)(tb + (size_t)(16 + l15) * 256 + ks * 32 + g * 8);
#pragma unroll
        for (int nf = 0; nf < 8; ++nf) {
            bf16x8 bq = *(const bf16x8*)(wqb + (size_t)(w * 128 + nf * 16 + l15) * 256 + ks * 32 + g * 8);
            acc[0][nf] = mfma16(a0, bq, acc[0][nf]);
            acc[1][nf] = mfma16(a1, bq, acc[1][nf]);
        }
    }
    // phase 2: per-head softmax over d (64 cols), * DH^-0.5, -> qsm LDS (bf16)
#pragma unroll
    for (int mf = 0; mf < 2; ++mf)
#pragma unroll
        for (int hh = 0; hh < 2; ++hh)
#pragma unroll
            for (int r = 0; r < 4; ++r) {
                float mx = -1e30f;
#pragma unroll
                for (int n2 = 0; n2 < 4; ++n2) mx = fmaxf(mx, acc[mf][hh * 4 + n2][r]);
                mx = fmaxf(mx, __shfl_xor(mx, 1));
                mx = fmaxf(mx, __shfl_xor(mx, 2));
                mx = fmaxf(mx, __shfl_xor(mx, 4));
                mx = fmaxf(mx, __shfl_xor(mx, 8));
                float p[4]; float sm = 0.f;
#pragma unroll
                for (int n2 = 0; n2 < 4; ++n2) { p[n2] = __expf(acc[mf][hh * 4 + n2][r] - mx); sm += p[n2]; }
                sm += __shfl_xor(sm, 1);
                sm += __shfl_xor(sm, 2);
                sm += __shfl_xor(sm, 4);
                sm += __shfl_xor(sm, 8);
                float scl = 0.125f / sm;
                int row = mf * 16 + g * 4 + r;
#pragma unroll
                for (int n2 = 0; n2 < 4; ++n2)
                    qsm[row][w * 128 + (hh * 4 + n2) * 16 + l15] = (bf16)(p[n2] * scl);
            }
    __syncthreads();
    // phase 3: out2 = qsm @ M2T  (wave w: 32 rows x cols [w*64, w*64+64) of 256)
    f32x4 acc2[2][4];
#pragma unroll
    for (int mf = 0; mf < 2; ++mf)
#pragma unroll
        for (int nf = 0; nf < 4; ++nf) acc2[mf][nf] = fz;
#pragma unroll
    for (int ks = 0; ks < 16; ++ks) {
        bf16x8 a0 = *(const bf16x8*)(&qsm[l15][ks * 32 + g * 8]);
        bf16x8 a1 = *(const bf16x8*)(&qsm[16 + l15][ks * 32 + g * 8]);
#pragma unroll
        for (int nf = 0; nf < 4; ++nf) {
            bf16x8 bm = *(const bf16x8*)(m2t + (size_t)(b * 256 + w * 64 + nf * 16 + l15) * 512 + ks * 32 + g * 8);
            acc2[0][nf] = mfma16(a0, bm, acc2[0][nf]);
            acc2[1][nf] = mfma16(a1, bm, acc2[1][nf]);
        }
    }
    // phase 4: +bias, rmsnorm over 256 cols, + xn residual, write [b][col][pix]
#pragma unroll
    for (int nf = 0; nf < 4; ++nf) {
        float bias = cb[w * 64 + nf * 16 + l15];
#pragma unroll
        for (int mf = 0; mf < 2; ++mf)
#pragma unroll
            for (int r = 0; r < 4; ++r) acc2[mf][nf][r] += bias;
    }
#pragma unroll
    for (int mf = 0; mf < 2; ++mf)
#pragma unroll
        for (int r = 0; r < 4; ++r) {
            float ssq = 0.f;
#pragma unroll
            for (int nf = 0; nf < 4; ++nf) ssq += acc2[mf][nf][r] * acc2[mf][nf][r];
            ssq += __shfl_xor(ssq, 1);
            ssq += __shfl_xor(ssq, 2);
            ssq += __shfl_xor(ssq, 4);
            ssq += __shfl_xor(ssq, 8);
            if (l15 == 0) rowsum[w][mf * 16 + g * 4 + r] = ssq;
        }
    __syncthreads();
#pragma unroll
    for (int mf = 0; mf < 2; ++mf) {
        int pixb = row0 + mf * 16 + g * 4;
        f32x4 ns4 = *(const f32x4*)(nscale + b * N_ + pixb);
        f32x4 scl4;
#pragma unroll
        for (int r = 0; r < 4; ++r) {
            int row = mf * 16 + g * 4 + r;
            float tot = rowsum[0][row] + rowsum[1][row] + rowsum[2][row] + rowsum[3][row];
            scl4[r] = 16.0f / fmaxf(sqrtf(tot), 1e-12f);
        }
#pragma unroll
        for (int nf = 0; nf < 4; ++nf) {
            int col = w * 64 + nf * 16 + l15;
            float gf = gffn[col], gn = gnorm[col];
            const float* xp = x + ((size_t)(b * 256 + col)) * N_ + pixb;
            f32x4 xv = *(const f32x4*)xp;
            f32x4 o4;
#pragma unroll
            for (int r = 0; r < 4; ++r)
                o4[r] = acc2[mf][nf][r] * scl4[r] * gf + xv[r] * ns4[r] * gn;
            *(f32x4*)(out + ((size_t)(b * 256 + col)) * N_ + pixb) = o4;
        }
    }
}

extern "C" void kernel_launch(void* const* d_in, const int* in_sizes, int n_in,
                              void* d_out, int out_size, void* d_ws, size_t ws_size,
                              hipStream_t stream) {
    const float* x     = (const float*)d_in[0];
    const float* Wq    = (const float*)d_in[1];
    const float* Wk    = (const float*)d_in[2];
    const float* Wv    = (const float*)d_in[3];
    const float* cw    = (const float*)d_in[4];
    const float* cb    = (const float*)d_in[5];
    const float* gffn  = (const float*)d_in[6];
    const float* gnorm = (const float*)d_in[7];
    char* ws = (char*)d_ws;
    bf16* t    = (bf16*)(ws + T_OFF);
    float* U   = (float*)(ws + U_OFF);
    float* S   = (float*)(ws + S_OFF);
    float* ns  = (float*)(ws + NS_OFF);
    bf16* m2t  = (bf16*)(ws + M2T_OFF);
    bf16* wqb  = (bf16*)(ws + WQ_OFF);
    bf16* wkb  = (bf16*)(ws + WK_OFF);
    bf16* wvb  = (bf16*)(ws + WV_OFF);
    float* out = (float*)d_out;

    hipMemsetAsync(U, 0, 1048576 + 16384, stream);  // U and S are contiguous
    k_cvtw<<<192, 256, 0, stream>>>(Wq, Wk, Wv, wqb, wkb, wvb);
    k_norm<<<512, 256, 0, stream>>>(x, gnorm, ns, t);
    k_kv<<<1024, 256, 0, stream>>>(t, wkb, wvb, U, S);
    k_attn_m2<<<256, 256, 0, stream>>>(U, S, cw, m2t);
    k_qout<<<1024, 256, 0, stream>>>(t, wqb, m2t, x, ns, gnorm, gffn, cb, out);
}

// Round 3
// 218.113 us; speedup vs baseline: 1.0632x; 1.0214x over previous
//
#include <hip/hip_runtime.h>
#include <hip/hip_bf16.h>

#define B_ 8
#define C_ 256
#define N_ 4096
#define HID_ 512

typedef __bf16 bf16;
typedef bf16 bf16x8 __attribute__((ext_vector_type(8)));
typedef bf16 bf16x4 __attribute__((ext_vector_type(4)));
typedef float f32x4 __attribute__((ext_vector_type(4)));

// ws layout (bytes)
#define T_OFF    0u           // t bf16 [B*N][256]            16 MB
#define U_OFF    16777216u    // U f32  [B][8][64][64]         1 MB
#define S_OFF    17825792u    // S f32  [B][8][64]            16 KB
#define NS_OFF   17842176u    // nscale f32 [B*N]            128 KB
#define M2T_OFF  17973248u    // M2T bf16 [B][256][512]        2 MB
#define WQ_OFF   20070400u    // Wq bf16 [512][256]          256 KB
#define WK_OFF   20332544u
#define WV_OFF   20594688u

__device__ __forceinline__ f32x4 mfma16(bf16x8 a, bf16x8 b, f32x4 c) {
    return __builtin_amdgcn_mfma_f32_16x16x32_bf16(a, b, c, 0, 0, 0);
}

__device__ __forceinline__ void gload_lds16(const void* g, void* l) {
    __builtin_amdgcn_global_load_lds(
        (const __attribute__((address_space(1))) unsigned int*)g,
        (__attribute__((address_space(3))) unsigned int*)l, 16, 0, 0);
}

// ---- convert 3 weight matrices fp32 -> bf16 ----
__global__ void __launch_bounds__(256) k_cvtw(const float* __restrict__ wq,
                                              const float* __restrict__ wk,
                                              const float* __restrict__ wv,
                                              bf16* __restrict__ oq,
                                              bf16* __restrict__ ok,
                                              bf16* __restrict__ ov) {
    int m = blockIdx.x >> 6;
    const float* src = (m == 0) ? wq : ((m == 1) ? wk : wv);
    bf16* dst = (m == 0) ? oq : ((m == 1) ? ok : ov);
    int i0 = ((blockIdx.x & 63) * 256 + threadIdx.x) * 8;
    f32x4 a = *(const f32x4*)(src + i0);
    f32x4 b = *(const f32x4*)(src + i0 + 4);
    bf16x8 o;
#pragma unroll
    for (int j = 0; j < 4; ++j) { o[j] = (bf16)a[j]; o[j + 4] = (bf16)b[j]; }
    *(bf16x8*)(dst + i0) = o;
}

// ---- rmsnorm scale + write t = xn (bf16, [row=pixel][c]) ----
__global__ void __launch_bounds__(256) k_norm(const float* __restrict__ x,
                                              const float* __restrict__ gnorm,
                                              float* __restrict__ nscale,
                                              bf16* __restrict__ t) {
    __shared__ float part[4][64];
    int b = blockIdx.x >> 6;
    int pix = ((blockIdx.x & 63) << 6) + (threadIdx.x & 63);
    int cq = threadIdx.x >> 6;
    const float* xb = x + (size_t)b * C_ * N_ + (size_t)(cq * 64) * N_ + pix;
    float xv[64];
    float ss = 0.f;
#pragma unroll 8
    for (int c = 0; c < 64; ++c) { xv[c] = xb[(size_t)c * N_]; ss += xv[c] * xv[c]; }
    part[cq][threadIdx.x & 63] = ss;
    __syncthreads();
    int p = threadIdx.x & 63;
    float tot = part[0][p] + part[1][p] + part[2][p] + part[3][p];
    float s = 16.0f / fmaxf(sqrtf(tot), 1e-12f);
    if (cq == 0) nscale[b * N_ + pix] = s;
    bf16* tb = t + ((size_t)(b * N_ + pix)) * C_ + cq * 64;
    for (int c0 = 0; c0 < 64; c0 += 8) {
        bf16x8 pk;
#pragma unroll
        for (int j = 0; j < 8; ++j)
            pk[j] = (bf16)(xv[c0 + j] * s * gnorm[cq * 64 + c0 + j]);
        *(bf16x8*)(tb + c0) = pk;
    }
}

// ---- fused KV projection + U = exp(K)^T V , S = colsum(exp(K)) ----
// grid: 512 = B * 64 row-splits (64 rows each); block 256 (4 waves).
// t tile staged ONCE in LDS (global_load_lds, XOR-swizzled via pre-swizzled source);
// all 8 heads computed from the staged tile -> t read exactly once from HBM.
__global__ void __launch_bounds__(256, 4) k_kv(const bf16* __restrict__ t,
                                               const bf16* __restrict__ wkb,
                                               const bf16* __restrict__ wvb,
                                               float* __restrict__ U,
                                               float* __restrict__ S) {
    __shared__ __align__(16) bf16 tS[64 * 256];   // 32 KB, rows of 512B, XOR-swizzled
    __shared__ __align__(16) bf16 ekT[64][72];    // [d][row] 9.2 KB
    __shared__ __align__(16) bf16 vT[64][72];     // [e][row]
    int sp = blockIdx.x & 63;
    int b = blockIdx.x >> 6;
    int w = threadIdx.x >> 6;
    int l = threadIdx.x & 63;
    int l15 = l & 15, g = l >> 4;
    int xorm = (l15 & 7) << 4;

    // stage t[64][256] -> LDS; dest linear, source pre-swizzled (involution XOR)
    const char* gt = (const char*)(t + (size_t)(b * N_ + sp * 64) * 256);
#pragma unroll
    for (int it = 0; it < 8; ++it) {
        int o = it * 4096 + w * 1024 + l * 16;
        int src = o ^ (((o >> 9) & 7) << 4);
        gload_lds16(gt + src, (char*)tS + it * 4096 + w * 1024);
    }

    const bf16* wsel = (w < 2) ? wkb : wvb;
    int c0 = (w & 1) * 32;
    bool isk = (w < 2);
    const f32x4 fz = {0.f, 0.f, 0.f, 0.f};
    __syncthreads();

    for (int h = 0; h < 8; ++h) {
        // stage-1: k/v = tS @ W^T ; wave w covers 32 cols of [k|v] for head h
        f32x4 acc[4][2];
#pragma unroll
        for (int mf = 0; mf < 4; ++mf) { acc[mf][0] = fz; acc[mf][1] = fz; }
#pragma unroll
        for (int ks = 0; ks < 8; ++ks) {
            bf16x8 w0 = *(const bf16x8*)(wsel + (size_t)(h * 64 + c0 + l15) * 256 + ks * 32 + g * 8);
            bf16x8 w1 = *(const bf16x8*)(wsel + (size_t)(h * 64 + c0 + 16 + l15) * 256 + ks * 32 + g * 8);
#pragma unroll
            for (int mf = 0; mf < 4; ++mf) {
                bf16x8 a = *(const bf16x8*)((const char*)tS + (mf * 16 + l15) * 512 + ((ks * 64 + g * 16) ^ xorm));
                acc[mf][0] = mfma16(a, w0, acc[mf][0]);
                acc[mf][1] = mfma16(a, w1, acc[mf][1]);
            }
        }
        __syncthreads();  // prior head's stage-2/S reads done before overwrite
#pragma unroll
        for (int mf = 0; mf < 4; ++mf)
#pragma unroll
            for (int nf = 0; nf < 2; ++nf) {
                int cc = c0 + nf * 16 + l15;
                int rr = mf * 16 + g * 4;
                bf16x4 pk;
#pragma unroll
                for (int r = 0; r < 4; ++r) {
                    float v = acc[mf][nf][r];
                    pk[r] = (bf16)(isk ? __expf(v) : v);
                }
                if (isk) *(bf16x4*)(&ekT[cc][rr]) = pk;
                else     *(bf16x4*)(&vT[cc][rr]) = pk;
            }
        __syncthreads();
        // stage-2: U[d][e0..e0+15] partial over 64 rows; e0 = w*16
        f32x4 uacc[4];
#pragma unroll
        for (int df = 0; df < 4; ++df) uacc[df] = fz;
#pragma unroll
        for (int k2 = 0; k2 < 2; ++k2) {
            bf16x8 bv = *(const bf16x8*)(&vT[w * 16 + l15][k2 * 32 + g * 8]);
#pragma unroll
            for (int df = 0; df < 4; ++df) {
                bf16x8 ae = *(const bf16x8*)(&ekT[df * 16 + l15][k2 * 32 + g * 8]);
                uacc[df] = mfma16(ae, bv, uacc[df]);
            }
        }
        // S partial (from the same bf16 exp(k) values for consistency)
        {
            int d = threadIdx.x & 63;
            int q = threadIdx.x >> 6;
            float sum = 0.f;
#pragma unroll
            for (int i = 0; i < 16; ++i) sum += (float)ekT[d][q * 16 + i];
            atomicAdd(S + ((b * 8 + h) * 64 + d), sum);
        }
        float* Ubh = U + ((size_t)(b * 8 + h)) * 4096;
#pragma unroll
        for (int df = 0; df < 4; ++df)
#pragma unroll
            for (int r = 0; r < 4; ++r)
                atomicAdd(Ubh + (df * 16 + g * 4 + r) * 64 + w * 16 + l15, uacc[df][r]);
    }
}

// ---- attn = U/S ; M2T[b][o][h*64+d] = sum_e attn[d][e] * conv_w[o][h*64+e] ----
__global__ void __launch_bounds__(256) k_attn_m2(const float* __restrict__ U,
                                                 const float* __restrict__ S,
                                                 const float* __restrict__ cw,
                                                 bf16* __restrict__ m2t) {
    __shared__ float at[16][64];
    int dq = blockIdx.x & 3, h = (blockIdx.x >> 2) & 7, b = blockIdx.x >> 5;
    int tid = threadIdx.x;
    const float* Ub = U + (size_t)(b * 8 + h) * 4096 + dq * 16 * 64;
    const float* Sb = S + (b * 8 + h) * 64 + dq * 16;
    for (int it = 0; it < 4; ++it) {
        int idx = it * 256 + tid;  // 0..1023
        at[idx >> 6][idx & 63] = Ub[idx] / Sb[idx >> 6];
    }
    __syncthreads();
    int o = tid;
    float cwr[64];
#pragma unroll
    for (int e = 0; e < 64; ++e) cwr[e] = cw[(size_t)o * 512 + h * 64 + e];
    bf16* dst = m2t + (size_t)(b * 256 + o) * 512 + h * 64 + dq * 16;
    for (int j0 = 0; j0 < 16; j0 += 8) {
        bf16x8 pk;
#pragma unroll
        for (int j = 0; j < 8; ++j) {
            float a2 = 0.f;
#pragma unroll
            for (int e = 0; e < 64; ++e) a2 += at[j0 + j][e] * cwr[e];
            pk[j] = (bf16)a2;
        }
        *(bf16x8*)(dst + j0) = pk;
    }
}

// ---- fused: q GEMM + per-head softmax + (qsm @ M2T) + bias + rmsnorm + residual ----
// grid 1024 = B * 128 row-tiles of 32; block 256 (4 waves)
__global__ void __launch_bounds__(256, 4) k_qout(const bf16* __restrict__ t,
                                                 const bf16* __restrict__ wqb,
                                                 const bf16* __restrict__ m2t,
                                                 const float* __restrict__ x,
                                                 const float* __restrict__ nscale,
                                                 const float* __restrict__ gnorm,
                                                 const float* __restrict__ gffn,
                                                 const float* __restrict__ cb,
                                                 float* __restrict__ out) {
    __shared__ __align__(16) bf16 qsm[32][520];
    __shared__ float rowsum[4][32];
    int b = blockIdx.x >> 7;
    int row0 = (blockIdx.x & 127) << 5;
    int w = threadIdx.x >> 6, l = threadIdx.x & 63;
    int l15 = l & 15, g = l >> 4;
    const f32x4 fz = {0.f, 0.f, 0.f, 0.f};

    // phase 1: q = t @ WqT   (wave w: 32 rows x cols [w*128, w*128+128))
    f32x4 acc[2][8];
#pragma unroll
    for (int mf = 0; mf < 2; ++mf)
#pragma unroll
        for (int nf = 0; nf < 8; ++nf) acc[mf][nf] = fz;
    const bf16* tb = t + (size_t)(b * N_ + row0) * 256;
#pragma unroll
    for (int ks = 0; ks < 8; ++ks) {
        bf16x8 a0 = *(const bf16x8*)(tb + (size_t)(l15) * 256 + ks * 32 + g * 8);
        bf16x8 a1 = *(const bf16x8*)(tb + (size_t)(16 + l15) * 256 + ks * 32 + g * 8);
#pragma unroll
        for (int nf = 0; nf < 8; ++nf) {
            bf16x8 bq = *(const bf16x8*)(wqb + (size_t)(w * 128 + nf * 16 + l15) * 256 + ks * 32 + g * 8);
            acc[0][nf] = mfma16(a0, bq, acc[0][nf]);
            acc[1][nf] = mfma16(a1, bq, acc[1][nf]);
        }
    }
    // phase 2: per-head softmax over d (64 cols), * DH^-0.5, -> qsm LDS (bf16)
#pragma unroll
    for (int mf = 0; mf < 2; ++mf)
#pragma unroll
        for (int hh = 0; hh < 2; ++hh)
#pragma unroll
            for (int r = 0; r < 4; ++r) {
                float mx = -1e30f;
#pragma unroll
                for (int n2 = 0; n2 < 4; ++n2) mx = fmaxf(mx, acc[mf][hh * 4 + n2][r]);
                mx = fmaxf(mx, __shfl_xor(mx, 1));
                mx = fmaxf(mx, __shfl_xor(mx, 2));
                mx = fmaxf(mx, __shfl_xor(mx, 4));
                mx = fmaxf(mx, __shfl_xor(mx, 8));
                float p[4]; float sm = 0.f;
#pragma unroll
                for (int n2 = 0; n2 < 4; ++n2) { p[n2] = __expf(acc[mf][hh * 4 + n2][r] - mx); sm += p[n2]; }
                sm += __shfl_xor(sm, 1);
                sm += __shfl_xor(sm, 2);
                sm += __shfl_xor(sm, 4);
                sm += __shfl_xor(sm, 8);
                float scl = 0.125f / sm;
                int row = mf * 16 + g * 4 + r;
#pragma unroll
                for (int n2 = 0; n2 < 4; ++n2)
                    qsm[row][w * 128 + (hh * 4 + n2) * 16 + l15] = (bf16)(p[n2] * scl);
            }
    __syncthreads();
    // phase 3: out2 = qsm @ M2T  (wave w: 32 rows x cols [w*64, w*64+64) of 256)
    f32x4 acc2[2][4];
#pragma unroll
    for (int mf = 0; mf < 2; ++mf)
#pragma unroll
        for (int nf = 0; nf < 4; ++nf) acc2[mf][nf] = fz;
#pragma unroll
    for (int ks = 0; ks < 16; ++ks) {
        bf16x8 a0 = *(const bf16x8*)(&qsm[l15][ks * 32 + g * 8]);
        bf16x8 a1 = *(const bf16x8*)(&qsm[16 + l15][ks * 32 + g * 8]);
#pragma unroll
        for (int nf = 0; nf < 4; ++nf) {
            bf16x8 bm = *(const bf16x8*)(m2t + (size_t)(b * 256 + w * 64 + nf * 16 + l15) * 512 + ks * 32 + g * 8);
            acc2[0][nf] = mfma16(a0, bm, acc2[0][nf]);
            acc2[1][nf] = mfma16(a1, bm, acc2[1][nf]);
        }
    }
    // phase 4: +bias, rmsnorm over 256 cols, + xn residual, write [b][col][pix]
#pragma unroll
    for (int nf = 0; nf < 4; ++nf) {
        float bias = cb[w * 64 + nf * 16 + l15];
#pragma unroll
        for (int mf = 0; mf < 2; ++mf)
#pragma unroll
            for (int r = 0; r < 4; ++r) acc2[mf][nf][r] += bias;
    }
#pragma unroll
    for (int mf = 0; mf < 2; ++mf)
#pragma unroll
        for (int r = 0; r < 4; ++r) {
            float ssq = 0.f;
#pragma unroll
            for (int nf = 0; nf < 4; ++nf) ssq += acc2[mf][nf][r] * acc2[mf][nf][r];
            ssq += __shfl_xor(ssq, 1);
            ssq += __shfl_xor(ssq, 2);
            ssq += __shfl_xor(ssq, 4);
            ssq += __shfl_xor(ssq, 8);
            if (l15 == 0) rowsum[w][mf * 16 + g * 4 + r] = ssq;
        }
    __syncthreads();
#pragma unroll
    for (int mf = 0; mf < 2; ++mf) {
        int pixb = row0 + mf * 16 + g * 4;
        f32x4 ns4 = *(const f32x4*)(nscale + b * N_ + pixb);
        f32x4 scl4;
#pragma unroll
        for (int r = 0; r < 4; ++r) {
            int row = mf * 16 + g * 4 + r;
            float tot = rowsum[0][row] + rowsum[1][row] + rowsum[2][row] + rowsum[3][row];
            scl4[r] = 16.0f / fmaxf(sqrtf(tot), 1e-12f);
        }
#pragma unroll
        for (int nf = 0; nf < 4; ++nf) {
            int col = w * 64 + nf * 16 + l15;
            float gf = gffn[col], gn = gnorm[col];
            const float* xp = x + ((size_t)(b * 256 + col)) * N_ + pixb;
            f32x4 xv = *(const f32x4*)xp;
            f32x4 o4;
#pragma unroll
            for (int r = 0; r < 4; ++r)
                o4[r] = acc2[mf][nf][r] * scl4[r] * gf + xv[r] * ns4[r] * gn;
            *(f32x4*)(out + ((size_t)(b * 256 + col)) * N_ + pixb) = o4;
        }
    }
}

extern "C" void kernel_launch(void* const* d_in, const int* in_sizes, int n_in,
                              void* d_out, int out_size, void* d_ws, size_t ws_size,
                              hipStream_t stream) {
    const float* x     = (const float*)d_in[0];
    const float* Wq    = (const float*)d_in[1];
    const float* Wk    = (const float*)d_in[2];
    const float* Wv    = (const float*)d_in[3];
    const float* cw    = (const float*)d_in[4];
    const float* cb    = (const float*)d_in[5];
    const float* gffn  = (const float*)d_in[6];
    const float* gnorm = (const float*)d_in[7];
    char* ws = (char*)d_ws;
    bf16* t    = (bf16*)(ws + T_OFF);
    float* U   = (float*)(ws + U_OFF);
    float* S   = (float*)(ws + S_OFF);
    float* ns  = (float*)(ws + NS_OFF);
    bf16* m2t  = (bf16*)(ws + M2T_OFF);
    bf16* wqb  = (bf16*)(ws + WQ_OFF);
    bf16* wkb  = (bf16*)(ws + WK_OFF);
    bf16* wvb  = (bf16*)(ws + WV_OFF);
    float* out = (float*)d_out;

    hipMemsetAsync(U, 0, 1048576 + 16384, stream);  // U and S are contiguous
    k_cvtw<<<192, 256, 0, stream>>>(Wq, Wk, Wv, wqb, wkb, wvb);
    k_norm<<<512, 256, 0, stream>>>(x, gnorm, ns, t);
    k_kv<<<512, 256, 0, stream>>>(t, wkb, wvb, U, S);
    k_attn_m2<<<256, 256, 0, stream>>>(U, S, cw, m2t);
    k_qout<<<1024, 256, 0, stream>>>(t, wqb, m2t, x, ns, gnorm, gffn, cb, out);
}

// Round 6
// 141.407 us; speedup vs baseline: 1.6399x; 1.5424x over previous
//
#include <hip/hip_runtime.h>
#include <hip/hip_bf16.h>

#define B_ 8
#define C_ 256
#define N_ 4096
#define HID_ 512

typedef __bf16 bf16;
typedef bf16 bf16x8 __attribute__((ext_vector_type(8)));
typedef bf16 bf16x4 __attribute__((ext_vector_type(4)));
typedef float f32x4 __attribute__((ext_vector_type(4)));

// ws layout (bytes) — EXACT round-3 footprint (20.9 MB, proven within ws_size).
// Round 4 grew this to 28.3 MB (U partials) and began failing with small
// distributed errors — suspected ws overrun. Do not exceed this footprint.
#define T_OFF    0u           // t bf16 [B*N][256]            16 MB
#define U_OFF    16777216u    // U f32  [B][8][64][64]         1 MB
#define S_OFF    17825792u    // S f32  [B][8][64]            16 KB
#define NS_OFF   17842176u    // nscale f32 [B*N]            128 KB
#define M2T_OFF  17973248u    // M2T bf16 [B][256][512]        2 MB
#define WQ_OFF   20070400u    // Wq bf16 [512][256]          256 KB
#define WK_OFF   20332544u
#define WV_OFF   20594688u

__device__ __forceinline__ f32x4 mfma16(bf16x8 a, bf16x8 b, f32x4 c) {
    return __builtin_amdgcn_mfma_f32_16x16x32_bf16(a, b, c, 0, 0, 0);
}

__device__ __forceinline__ void gload_lds16(const void* g, void* l) {
    __builtin_amdgcn_global_load_lds(
        (const __attribute__((address_space(1))) unsigned int*)g,
        (__attribute__((address_space(3))) unsigned int*)l, 16, 0, 0);
}

// ---- convert 3 weight matrices fp32 -> bf16 ----
__global__ void __launch_bounds__(256) k_cvtw(const float* __restrict__ wq,
                                              const float* __restrict__ wk,
                                              const float* __restrict__ wv,
                                              bf16* __restrict__ oq,
                                              bf16* __restrict__ ok,
                                              bf16* __restrict__ ov) {
    int m = blockIdx.x >> 6;
    const float* src = (m == 0) ? wq : ((m == 1) ? wk : wv);
    bf16* dst = (m == 0) ? oq : ((m == 1) ? ok : ov);
    int i0 = ((blockIdx.x & 63) * 256 + threadIdx.x) * 8;
    f32x4 a = *(const f32x4*)(src + i0);
    f32x4 b = *(const f32x4*)(src + i0 + 4);
    bf16x8 o;
#pragma unroll
    for (int j = 0; j < 4; ++j) { o[j] = (bf16)a[j]; o[j + 4] = (bf16)b[j]; }
    *(bf16x8*)(dst + i0) = o;
}

// ---- rmsnorm scale + write t = xn (bf16, [row=pixel][c]) ----
// FULL unroll: xv[64] static indices -> registers (partial unroll spilled to scratch).
__global__ void __launch_bounds__(256, 4) k_norm(const float* __restrict__ x,
                                                 const float* __restrict__ gnorm,
                                                 float* __restrict__ nscale,
                                                 bf16* __restrict__ t) {
    __shared__ float part[4][64];
    int b = blockIdx.x >> 6;
    int pix = ((blockIdx.x & 63) << 6) + (threadIdx.x & 63);
    int cq = threadIdx.x >> 6;
    const float* xb = x + (size_t)b * C_ * N_ + (size_t)(cq * 64) * N_ + pix;
    float xv[64];
    float ss = 0.f;
#pragma unroll
    for (int c = 0; c < 64; ++c) { xv[c] = xb[(size_t)c * N_]; ss += xv[c] * xv[c]; }
    part[cq][threadIdx.x & 63] = ss;
    __syncthreads();
    int p = threadIdx.x & 63;
    float tot = part[0][p] + part[1][p] + part[2][p] + part[3][p];
    float s = 16.0f / fmaxf(sqrtf(tot), 1e-12f);
    if (cq == 0) nscale[b * N_ + pix] = s;
    bf16* tb = t + ((size_t)(b * N_ + pix)) * C_ + cq * 64;
#pragma unroll
    for (int c0 = 0; c0 < 64; c0 += 8) {
        bf16x8 pk;
#pragma unroll
        for (int j = 0; j < 8; ++j)
            pk[j] = (bf16)(xv[c0 + j] * s * gnorm[cq * 64 + c0 + j]);
        *(bf16x8*)(tb + c0) = pk;
    }
}

// ---- fused KV projection + U = exp(K)^T V , S = colsum(exp(K)) ----
// grid 512 = h(8) x b(8) x chunk(8 of 512 rows). One head per block; head weights
// register-resident; U accumulated in REGISTERS across the chunk's 8 tiles, then
// ONE atomicAdd commit per element (r2-proven). S via r3-proven scalar ekT sums,
// register-accumulated, one atomicAdd per thread. U/S zeroed by memset.
// blockIdx mod 8 == chunk: the 8 h-blocks sharing a t-chunk land on one XCD.
__global__ void __launch_bounds__(256, 2) k_kv(const bf16* __restrict__ t,
                                               const bf16* __restrict__ wkb,
                                               const bf16* __restrict__ wvb,
                                               float* __restrict__ U,
                                               float* __restrict__ S) {
    __shared__ __align__(16) bf16 tS[64 * 256];   // 32 KB, rows 512B, XOR-swizzled
    __shared__ __align__(16) bf16 ekT[64][72];    // stride 144B = 9*16 (b128-aligned)
    __shared__ __align__(16) bf16 vT[64][72];
    int h = blockIdx.x >> 6;
    int b = (blockIdx.x >> 3) & 7;
    int chunk = blockIdx.x & 7;
    int w = threadIdx.x >> 6;
    int l = threadIdx.x & 63;
    int l15 = l & 15, g = l >> 4;
    int xorm = (l15 & 7) << 4;

    const bf16* wsel = (w < 2) ? wkb : wvb;
    int c0 = (w & 1) * 32;
    bool isk = (w < 2);
    // head weights in registers: wave covers 32 cols of [k|v]; 64 VGPRs, loaded once
    bf16x8 wf[2][8];
#pragma unroll
    for (int nf = 0; nf < 2; ++nf)
#pragma unroll
        for (int ks = 0; ks < 8; ++ks)
            wf[nf][ks] = *(const bf16x8*)(wsel + (size_t)(h * 64 + c0 + nf * 16 + l15) * 256 + ks * 32 + g * 8);

    const f32x4 fz = {0.f, 0.f, 0.f, 0.f};
    f32x4 uacc[4];
#pragma unroll
    for (int df = 0; df < 4; ++df) uacc[df] = fz;
    float sreg = 0.f;

    size_t rowbase = (size_t)b * N_ + chunk * 512;
    for (int tile = 0; tile < 8; ++tile) {
        // stage t[64][256] -> LDS (dest linear, source pre-swizzled involution)
        {
            const char* gt = (const char*)(t + (rowbase + tile * 64) * 256);
#pragma unroll
            for (int it = 0; it < 8; ++it) {
                int o = it * 4096 + w * 1024 + l * 16;
                int src = o ^ (((o >> 9) & 7) << 4);
                gload_lds16(gt + src, (char*)tS + it * 4096 + w * 1024);
            }
        }
        __syncthreads();  // vmcnt drained -> tS ready
        // stage-1: k/v = tS @ W^T for this head
        f32x4 acc[4][2];
#pragma unroll
        for (int mf = 0; mf < 4; ++mf) { acc[mf][0] = fz; acc[mf][1] = fz; }
#pragma unroll
        for (int ks = 0; ks < 8; ++ks) {
#pragma unroll
            for (int mf = 0; mf < 4; ++mf) {
                bf16x8 a = *(const bf16x8*)((const char*)tS + (mf * 16 + l15) * 512 + ((ks * 64 + g * 16) ^ xorm));
                acc[mf][0] = mfma16(a, wf[0][ks], acc[mf][0]);
                acc[mf][1] = mfma16(a, wf[1][ks], acc[mf][1]);
            }
        }
        __syncthreads();  // stage-1 tS reads + prev stage-2/S ekT/vT reads done
#pragma unroll
        for (int mf = 0; mf < 4; ++mf)
#pragma unroll
            for (int nf = 0; nf < 2; ++nf) {
                int cc = c0 + nf * 16 + l15;
                int rr = mf * 16 + g * 4;
                bf16x4 pk;
#pragma unroll
                for (int r = 0; r < 4; ++r) {
                    float v = acc[mf][nf][r];
                    pk[r] = (bf16)(isk ? __expf(v) : v);
                }
                if (isk) *(bf16x4*)(&ekT[cc][rr]) = pk;
                else     *(bf16x4*)(&vT[cc][rr]) = pk;
            }
        __syncthreads();  // ekT/vT ready
        // stage-2: U += expK^T V over this tile's 64 rows
#pragma unroll
        for (int k2 = 0; k2 < 2; ++k2) {
            bf16x8 bv = *(const bf16x8*)(&vT[w * 16 + l15][k2 * 32 + g * 8]);
#pragma unroll
            for (int df = 0; df < 4; ++df) {
                bf16x8 ae = *(const bf16x8*)(&ekT[df * 16 + l15][k2 * 32 + g * 8]);
                uacc[df] = mfma16(ae, bv, uacc[df]);
            }
        }
        // S partial: thread (d=l, rows w*16..w*16+15), r3-proven scalar path
        {
#pragma unroll
            for (int i = 0; i < 16; ++i) sreg += (float)ekT[l][w * 16 + i];
        }
    }
    // commit: one atomicAdd per U element-slot, one per S slot
    int bh = b * 8 + h;
    float* Ubh = U + (size_t)bh * 4096;
#pragma unroll
    for (int df = 0; df < 4; ++df)
#pragma unroll
        for (int r = 0; r < 4; ++r)
            atomicAdd(Ubh + (df * 16 + g * 4 + r) * 64 + w * 16 + l15, uacc[df][r]);
    atomicAdd(S + bh * 64 + l, sreg);
}

// ---- attn = U/S ; M2T[b][o][h*64+d] = sum_e attn[d][e] * conv_w[o][h*64+e] ----
// grid 256 = (b, h, d-quarter); block 256 (one thread per output channel o). r3 exact.
__global__ void __launch_bounds__(256) k_attn_m2(const float* __restrict__ U,
                                                 const float* __restrict__ S,
                                                 const float* __restrict__ cw,
                                                 bf16* __restrict__ m2t) {
    __shared__ float at[16][64];
    int dq = blockIdx.x & 3, h = (blockIdx.x >> 2) & 7, b = blockIdx.x >> 5;
    int tid = threadIdx.x;
    const float* Ub = U + (size_t)(b * 8 + h) * 4096 + dq * 16 * 64;
    const float* Sb = S + (b * 8 + h) * 64 + dq * 16;
    for (int it = 0; it < 4; ++it) {
        int idx = it * 256 + tid;  // 0..1023
        at[idx >> 6][idx & 63] = Ub[idx] / Sb[idx >> 6];
    }
    __syncthreads();
    int o = tid;
    float cwr[64];
#pragma unroll
    for (int e = 0; e < 64; ++e) cwr[e] = cw[(size_t)o * 512 + h * 64 + e];
    bf16* dst = m2t + (size_t)(b * 256 + o) * 512 + h * 64 + dq * 16;
    for (int j0 = 0; j0 < 16; j0 += 8) {
        bf16x8 pk;
#pragma unroll
        for (int j = 0; j < 8; ++j) {
            float a2 = 0.f;
#pragma unroll
            for (int e = 0; e < 64; ++e) a2 += at[j0 + j][e] * cwr[e];
            pk[j] = (bf16)a2;
        }
        *(bf16x8*)(dst + j0) = pk;
    }
}

// ---- fused: q GEMM + per-head softmax + (qsm @ M2T) + bias + rmsnorm + residual ----
// grid 1024 = B * 128 row-tiles of 32; block 256 (4 waves).
// t-tile staged via swizzled global_load_lds into LDS (union'd with qsm).
// qsm stride 520 elems = 1040B = 65*16 — keep multiple of 8 elems for b128.
__global__ void __launch_bounds__(256, 4) k_qout(const bf16* __restrict__ t,
                                                 const bf16* __restrict__ wqb,
                                                 const bf16* __restrict__ m2t,
                                                 const float* __restrict__ x,
                                                 const float* __restrict__ nscale,
                                                 const float* __restrict__ gnorm,
                                                 const float* __restrict__ gffn,
                                                 const float* __restrict__ cb,
                                                 float* __restrict__ out) {
    __shared__ __align__(16) bf16 qsm[32][520];   // 33.3 KB; first 16KB doubles as t-tile
    __shared__ float rowsum[4][32];
    bf16* tS = &qsm[0][0];
    int b = blockIdx.x >> 7;
    int row0 = (blockIdx.x & 127) << 5;
    int w = threadIdx.x >> 6, l = threadIdx.x & 63;
    int l15 = l & 15, g = l >> 4;
    int xorm = (l15 & 7) << 4;
    const f32x4 fz = {0.f, 0.f, 0.f, 0.f};

    // stage t[32][256] (16KB) swizzled
    {
        const char* gt = (const char*)(t + (size_t)(b * N_ + row0) * 256);
        int tid = threadIdx.x;
#pragma unroll
        for (int it = 0; it < 4; ++it) {
            int o = it * 4096 + tid * 16;
            int src = o ^ (((o >> 9) & 7) << 4);
            gload_lds16(gt + src, (char*)tS + o);
        }
    }
    __syncthreads();  // drains vmcnt -> tS ready

    // phase 1: q = tS @ WqT   (wave w: 32 rows x cols [w*128, w*128+128))
    f32x4 acc[2][8];
#pragma unroll
    for (int mf = 0; mf < 2; ++mf)
#pragma unroll
        for (int nf = 0; nf < 8; ++nf) acc[mf][nf] = fz;
#pragma unroll
    for (int ks = 0; ks < 8; ++ks) {
        bf16x8 a0 = *(const bf16x8*)((const char*)tS + (l15) * 512 + ((ks * 64 + g * 16) ^ xorm));
        bf16x8 a1 = *(const bf16x8*)((const char*)tS + (16 + l15) * 512 + ((ks * 64 + g * 16) ^ xorm));
#pragma unroll
        for (int nf = 0; nf < 8; ++nf) {
            bf16x8 bq = *(const bf16x8*)(wqb + (size_t)(w * 128 + nf * 16 + l15) * 256 + ks * 32 + g * 8);
            acc[0][nf] = mfma16(a0, bq, acc[0][nf]);
            acc[1][nf] = mfma16(a1, bq, acc[1][nf]);
        }
    }
    __syncthreads();  // all tS reads done before qsm overwrite
    // phase 2: per-head softmax over d (64 cols), * DH^-0.5, -> qsm LDS (bf16)
#pragma unroll
    for (int mf = 0; mf < 2; ++mf)
#pragma unroll
        for (int hh = 0; hh < 2; ++hh)
#pragma unroll
            for (int r = 0; r < 4; ++r) {
                float mx = -1e30f;
#pragma unroll
                for (int n2 = 0; n2 < 4; ++n2) mx = fmaxf(mx, acc[mf][hh * 4 + n2][r]);
                mx = fmaxf(mx, __shfl_xor(mx, 1));
                mx = fmaxf(mx, __shfl_xor(mx, 2));
                mx = fmaxf(mx, __shfl_xor(mx, 4));
                mx = fmaxf(mx, __shfl_xor(mx, 8));
                float p[4]; float sm = 0.f;
#pragma unroll
                for (int n2 = 0; n2 < 4; ++n2) { p[n2] = __expf(acc[mf][hh * 4 + n2][r] - mx); sm += p[n2]; }
                sm += __shfl_xor(sm, 1);
                sm += __shfl_xor(sm, 2);
                sm += __shfl_xor(sm, 4);
                sm += __shfl_xor(sm, 8);
                float scl = 0.125f / sm;
                int row = mf * 16 + g * 4 + r;
#pragma unroll
                for (int n2 = 0; n2 < 4; ++n2)
                    qsm[row][w * 128 + (hh * 4 + n2) * 16 + l15] = (bf16)(p[n2] * scl);
            }
    __syncthreads();
    // phase 3: out2 = qsm @ M2T  (wave w: 32 rows x cols [w*64, w*64+64) of 256)
    f32x4 acc2[2][4];
#pragma unroll
    for (int mf = 0; mf < 2; ++mf)
#pragma unroll
        for (int nf = 0; nf < 4; ++nf) acc2[mf][nf] = fz;
#pragma unroll
    for (int ks = 0; ks < 16; ++ks) {
        bf16x8 a0 = *(const bf16x8*)(&qsm[l15][ks * 32 + g * 8]);
        bf16x8 a1 = *(const bf16x8*)(&qsm[16 + l15][ks * 32 + g * 8]);
#pragma unroll
        for (int nf = 0; nf < 4; ++nf) {
            bf16x8 bm = *(const bf16x8*)(m2t + (size_t)(b * 256 + w * 64 + nf * 16 + l15) * 512 + ks * 32 + g * 8);
            acc2[0][nf] = mfma16(a0, bm, acc2[0][nf]);
            acc2[1][nf] = mfma16(a1, bm, acc2[1][nf]);
        }
    }
    // phase 4: +bias, rmsnorm over 256 cols, + xn residual, write [b][col][pix]
#pragma unroll
    for (int nf = 0; nf < 4; ++nf) {
        float bias = cb[w * 64 + nf * 16 + l15];
#pragma unroll
        for (int mf = 0; mf < 2; ++mf)
#pragma unroll
            for (int r = 0; r < 4; ++r) acc2[mf][nf][r] += bias;
    }
#pragma unroll
    for (int mf = 0; mf < 2; ++mf)
#pragma unroll
        for (int r = 0; r < 4; ++r) {
            float ssq = 0.f;
#pragma unroll
            for (int nf = 0; nf < 4; ++nf) ssq += acc2[mf][nf][r] * acc2[mf][nf][r];
            ssq += __shfl_xor(ssq, 1);
            ssq += __shfl_xor(ssq, 2);
            ssq += __shfl_xor(ssq, 4);
            ssq += __shfl_xor(ssq, 8);
            if (l15 == 0) rowsum[w][mf * 16 + g * 4 + r] = ssq;
        }
    __syncthreads();
#pragma unroll
    for (int mf = 0; mf < 2; ++mf) {
        int pixb = row0 + mf * 16 + g * 4;
        f32x4 ns4 = *(const f32x4*)(nscale + b * N_ + pixb);
        f32x4 scl4;
#pragma unroll
        for (int r = 0; r < 4; ++r) {
            int row = mf * 16 + g * 4 + r;
            float tot = rowsum[0][row] + rowsum[1][row] + rowsum[2][row] + rowsum[3][row];
            scl4[r] = 16.0f / fmaxf(sqrtf(tot), 1e-12f);
        }
#pragma unroll
        for (int nf = 0; nf < 4; ++nf) {
            int col = w * 64 + nf * 16 + l15;
            float gf = gffn[col], gn = gnorm[col];
            const float* xp = x + ((size_t)(b * 256 + col)) * N_ + pixb;
            f32x4 xv = *(const f32x4*)xp;
            f32x4 o4;
#pragma unroll
            for (int r = 0; r < 4; ++r)
                o4[r] = acc2[mf][nf][r] * scl4[r] * gf + xv[r] * ns4[r] * gn;
            *(f32x4*)(out + ((size_t)(b * 256 + col)) * N_ + pixb) = o4;
        }
    }
}

extern "C" void kernel_launch(void* const* d_in, const int* in_sizes, int n_in,
                              void* d_out, int out_size, void* d_ws, size_t ws_size,
                              hipStream_t stream) {
    const float* x     = (const float*)d_in[0];
    const float* Wq    = (const float*)d_in[1];
    const float* Wk    = (const float*)d_in[2];
    const float* Wv    = (const float*)d_in[3];
    const float* cw    = (const float*)d_in[4];
    const float* cb    = (const float*)d_in[5];
    const float* gffn  = (const float*)d_in[6];
    const float* gnorm = (const float*)d_in[7];
    char* ws = (char*)d_ws;
    bf16* t    = (bf16*)(ws + T_OFF);
    float* U   = (float*)(ws + U_OFF);
    float* S   = (float*)(ws + S_OFF);
    float* ns  = (float*)(ws + NS_OFF);
    bf16* m2t  = (bf16*)(ws + M2T_OFF);
    bf16* wqb  = (bf16*)(ws + WQ_OFF);
    bf16* wkb  = (bf16*)(ws + WK_OFF);
    bf16* wvb  = (bf16*)(ws + WV_OFF);
    float* out = (float*)d_out;

    hipMemsetAsync(U, 0, 1048576 + 16384, stream);  // U and S are contiguous
    k_cvtw<<<192, 256, 0, stream>>>(Wq, Wk, Wv, wqb, wkb, wvb);
    k_norm<<<512, 256, 0, stream>>>(x, gnorm, ns, t);
    k_kv<<<512, 256, 0, stream>>>(t, wkb, wvb, U, S);
    k_attn_m2<<<256, 256, 0, stream>>>(U, S, cw, m2t);
    k_qout<<<1024, 256, 0, stream>>>(t, wqb, m2t, x, ns, gnorm, gffn, cb, out);
}

// Round 7
// 141.058 us; speedup vs baseline: 1.6440x; 1.0025x over previous
//
#include <hip/hip_runtime.h>
#include <hip/hip_bf16.h>

#define B_ 8
#define C_ 256
#define N_ 4096
#define HID_ 512

typedef __bf16 bf16;
typedef bf16 bf16x8 __attribute__((ext_vector_type(8)));
typedef bf16 bf16x4 __attribute__((ext_vector_type(4)));
typedef float f32x4 __attribute__((ext_vector_type(4)));

// ws layout (bytes) — round-3 footprint (20.9 MB, proven within ws_size). Do not grow.
#define T_OFF    0u           // t bf16 [B*N][256]            16 MB   (t == xn, incl. g_norm)
#define U_OFF    16777216u    // U f32  [B][8][64][64]         1 MB
#define S_OFF    17825792u    // S f32  [B][8][64]            16 KB
#define M2T_OFF  17973248u    // M2T bf16 [B][256][512]        2 MB
#define WQ_OFF   20070400u    // Wq bf16 [512][256]          256 KB
#define WK_OFF   20332544u
#define WV_OFF   20594688u

__device__ __forceinline__ f32x4 mfma16(bf16x8 a, bf16x8 b, f32x4 c) {
    return __builtin_amdgcn_mfma_f32_16x16x32_bf16(a, b, c, 0, 0, 0);
}

__device__ __forceinline__ void gload_lds16(const void* g, void* l) {
    __builtin_amdgcn_global_load_lds(
        (const __attribute__((address_space(1))) unsigned int*)g,
        (__attribute__((address_space(3))) unsigned int*)l, 16, 0, 0);
}

// ---- fused: rmsnorm->t (blocks 0..511) + weight cvt fp32->bf16 (blocks 512..703) ----
__global__ void __launch_bounds__(256, 4) k_nc(const float* __restrict__ x,
                                               const float* __restrict__ gnorm,
                                               bf16* __restrict__ t,
                                               const float* __restrict__ wq,
                                               const float* __restrict__ wk,
                                               const float* __restrict__ wv,
                                               bf16* __restrict__ oq,
                                               bf16* __restrict__ ok,
                                               bf16* __restrict__ ov) {
    if (blockIdx.x >= 512) {
        int bb = blockIdx.x - 512;
        int m = bb >> 6;
        const float* src = (m == 0) ? wq : ((m == 1) ? wk : wv);
        bf16* dst = (m == 0) ? oq : ((m == 1) ? ok : ov);
        int i0 = ((bb & 63) * 256 + threadIdx.x) * 8;
        f32x4 a = *(const f32x4*)(src + i0);
        f32x4 b = *(const f32x4*)(src + i0 + 4);
        bf16x8 o;
#pragma unroll
        for (int j = 0; j < 4; ++j) { o[j] = (bf16)a[j]; o[j + 4] = (bf16)b[j]; }
        *(bf16x8*)(dst + i0) = o;
        return;
    }
    __shared__ float part[4][64];
    int b = blockIdx.x >> 6;
    int pix = ((blockIdx.x & 63) << 6) + (threadIdx.x & 63);
    int cq = threadIdx.x >> 6;
    const float* xb = x + (size_t)b * C_ * N_ + (size_t)(cq * 64) * N_ + pix;
    float xv[64];
    float ss = 0.f;
#pragma unroll
    for (int c = 0; c < 64; ++c) { xv[c] = xb[(size_t)c * N_]; ss += xv[c] * xv[c]; }
    part[cq][threadIdx.x & 63] = ss;
    __syncthreads();
    int p = threadIdx.x & 63;
    float tot = part[0][p] + part[1][p] + part[2][p] + part[3][p];
    float s = 16.0f / fmaxf(sqrtf(tot), 1e-12f);
    bf16* tb = t + ((size_t)(b * N_ + pix)) * C_ + cq * 64;
#pragma unroll
    for (int c0 = 0; c0 < 64; c0 += 8) {
        bf16x8 pk;
#pragma unroll
        for (int j = 0; j < 8; ++j)
            pk[j] = (bf16)(xv[c0 + j] * s * gnorm[cq * 64 + c0 + j]);
        *(bf16x8*)(tb + c0) = pk;
    }
}

// ---- fused KV projection + U = exp(K)^T V , S = colsum(exp(K)) ---- (r6-proven)
__global__ void __launch_bounds__(256, 2) k_kv(const bf16* __restrict__ t,
                                               const bf16* __restrict__ wkb,
                                               const bf16* __restrict__ wvb,
                                               float* __restrict__ U,
                                               float* __restrict__ S) {
    __shared__ __align__(16) bf16 tS[64 * 256];   // 32 KB, rows 512B, XOR-swizzled
    __shared__ __align__(16) bf16 ekT[64][72];    // stride 144B = 9*16 (b128-aligned)
    __shared__ __align__(16) bf16 vT[64][72];
    int h = blockIdx.x >> 6;
    int b = (blockIdx.x >> 3) & 7;
    int chunk = blockIdx.x & 7;
    int w = threadIdx.x >> 6;
    int l = threadIdx.x & 63;
    int l15 = l & 15, g = l >> 4;
    int xorm = (l15 & 7) << 4;

    const bf16* wsel = (w < 2) ? wkb : wvb;
    int c0 = (w & 1) * 32;
    bool isk = (w < 2);
    bf16x8 wf[2][8];
#pragma unroll
    for (int nf = 0; nf < 2; ++nf)
#pragma unroll
        for (int ks = 0; ks < 8; ++ks)
            wf[nf][ks] = *(const bf16x8*)(wsel + (size_t)(h * 64 + c0 + nf * 16 + l15) * 256 + ks * 32 + g * 8);

    const f32x4 fz = {0.f, 0.f, 0.f, 0.f};
    f32x4 uacc[4];
#pragma unroll
    for (int df = 0; df < 4; ++df) uacc[df] = fz;
    float sreg = 0.f;

    size_t rowbase = (size_t)b * N_ + chunk * 512;
    for (int tile = 0; tile < 8; ++tile) {
        {
            const char* gt = (const char*)(t + (rowbase + tile * 64) * 256);
#pragma unroll
            for (int it = 0; it < 8; ++it) {
                int o = it * 4096 + w * 1024 + l * 16;
                int src = o ^ (((o >> 9) & 7) << 4);
                gload_lds16(gt + src, (char*)tS + it * 4096 + w * 1024);
            }
        }
        __syncthreads();  // vmcnt drained -> tS ready
        f32x4 acc[4][2];
#pragma unroll
        for (int mf = 0; mf < 4; ++mf) { acc[mf][0] = fz; acc[mf][1] = fz; }
#pragma unroll
        for (int ks = 0; ks < 8; ++ks) {
#pragma unroll
            for (int mf = 0; mf < 4; ++mf) {
                bf16x8 a = *(const bf16x8*)((const char*)tS + (mf * 16 + l15) * 512 + ((ks * 64 + g * 16) ^ xorm));
                acc[mf][0] = mfma16(a, wf[0][ks], acc[mf][0]);
                acc[mf][1] = mfma16(a, wf[1][ks], acc[mf][1]);
            }
        }
        __syncthreads();  // stage-1 tS reads + prev stage-2/S ekT/vT reads done
#pragma unroll
        for (int mf = 0; mf < 4; ++mf)
#pragma unroll
            for (int nf = 0; nf < 2; ++nf) {
                int cc = c0 + nf * 16 + l15;
                int rr = mf * 16 + g * 4;
                bf16x4 pk;
#pragma unroll
                for (int r = 0; r < 4; ++r) {
                    float v = acc[mf][nf][r];
                    pk[r] = (bf16)(isk ? __expf(v) : v);
                }
                if (isk) *(bf16x4*)(&ekT[cc][rr]) = pk;
                else     *(bf16x4*)(&vT[cc][rr]) = pk;
            }
        __syncthreads();  // ekT/vT ready
#pragma unroll
        for (int k2 = 0; k2 < 2; ++k2) {
            bf16x8 bv = *(const bf16x8*)(&vT[w * 16 + l15][k2 * 32 + g * 8]);
#pragma unroll
            for (int df = 0; df < 4; ++df) {
                bf16x8 ae = *(const bf16x8*)(&ekT[df * 16 + l15][k2 * 32 + g * 8]);
                uacc[df] = mfma16(ae, bv, uacc[df]);
            }
        }
        {
#pragma unroll
            for (int i = 0; i < 16; ++i) sreg += (float)ekT[l][w * 16 + i];
        }
    }
    int bh = b * 8 + h;
    float* Ubh = U + (size_t)bh * 4096;
#pragma unroll
    for (int df = 0; df < 4; ++df)
#pragma unroll
        for (int r = 0; r < 4; ++r)
            atomicAdd(Ubh + (df * 16 + g * 4 + r) * 64 + w * 16 + l15, uacc[df][r]);
    atomicAdd(S + bh * 64 + l, sreg);
}

// ---- attn = U/S ; M2T[b][o][h*64+d] = sum_e attn[d][e] * conv_w[o][h*64+e] ----
__global__ void __launch_bounds__(256) k_attn_m2(const float* __restrict__ U,
                                                 const float* __restrict__ S,
                                                 const float* __restrict__ cw,
                                                 bf16* __restrict__ m2t) {
    __shared__ float at[16][64];
    int dq = blockIdx.x & 3, h = (blockIdx.x >> 2) & 7, b = blockIdx.x >> 5;
    int tid = threadIdx.x;
    const float* Ub = U + (size_t)(b * 8 + h) * 4096 + dq * 16 * 64;
    const float* Sb = S + (b * 8 + h) * 64 + dq * 16;
    for (int it = 0; it < 4; ++it) {
        int idx = it * 256 + tid;  // 0..1023
        at[idx >> 6][idx & 63] = Ub[idx] / Sb[idx >> 6];
    }
    __syncthreads();
    int o = tid;
    float cwr[64];
#pragma unroll
    for (int e = 0; e < 64; ++e) cwr[e] = cw[(size_t)o * 512 + h * 64 + e];
    bf16* dst = m2t + (size_t)(b * 256 + o) * 512 + h * 64 + dq * 16;
    for (int j0 = 0; j0 < 16; j0 += 8) {
        bf16x8 pk;
#pragma unroll
        for (int j = 0; j < 8; ++j) {
            float a2 = 0.f;
#pragma unroll
            for (int e = 0; e < 64; ++e) a2 += at[j0 + j][e] * cwr[e];
            pk[j] = (bf16)a2;
        }
        *(bf16x8*)(dst + j0) = pk;
    }
}

// ---- fused: q GEMM + per-head softmax + (qsm @ M2T) + bias + rmsnorm + residual ----
// grid 1024 = B * 128 row-tiles of 32; block 256 (4 waves).
// t-tile staged swizzled into LDS (union'd with qsm). Residual xn == t: captured
// from tS into registers BEFORE qsm overwrites it -> no x/nscale/gnorm reads at all.
__global__ void __launch_bounds__(256, 4) k_qout(const bf16* __restrict__ t,
                                                 const bf16* __restrict__ wqb,
                                                 const bf16* __restrict__ m2t,
                                                 const float* __restrict__ gffn,
                                                 const float* __restrict__ cb,
                                                 float* __restrict__ out) {
    __shared__ __align__(16) bf16 qsm[32][520];   // 33.3 KB; first 16KB doubles as t-tile
    __shared__ float rowsum[4][32];
    bf16* tS = &qsm[0][0];
    int b = blockIdx.x >> 7;
    int row0 = (blockIdx.x & 127) << 5;
    int w = threadIdx.x >> 6, l = threadIdx.x & 63;
    int l15 = l & 15, g = l >> 4;
    int xorm = (l15 & 7) << 4;
    const f32x4 fz = {0.f, 0.f, 0.f, 0.f};

    // stage t[32][256] (16KB) swizzled
    {
        const char* gt = (const char*)(t + (size_t)(b * N_ + row0) * 256);
        int tid = threadIdx.x;
#pragma unroll
        for (int it = 0; it < 4; ++it) {
            int o = it * 4096 + tid * 16;
            int src = o ^ (((o >> 9) & 7) << 4);
            gload_lds16(gt + src, (char*)tS + o);
        }
    }
    __syncthreads();  // drains vmcnt -> tS ready

    // phase 1: q = tS @ WqT   (wave w: 32 rows x cols [w*128, w*128+128))
    f32x4 acc[2][8];
#pragma unroll
    for (int mf = 0; mf < 2; ++mf)
#pragma unroll
        for (int nf = 0; nf < 8; ++nf) acc[mf][nf] = fz;
#pragma unroll
    for (int ks = 0; ks < 8; ++ks) {
        bf16x8 a0 = *(const bf16x8*)((const char*)tS + (l15) * 512 + ((ks * 64 + g * 16) ^ xorm));
        bf16x8 a1 = *(const bf16x8*)((const char*)tS + (16 + l15) * 512 + ((ks * 64 + g * 16) ^ xorm));
#pragma unroll
        for (int nf = 0; nf < 8; ++nf) {
            bf16x8 bq = *(const bf16x8*)(wqb + (size_t)(w * 128 + nf * 16 + l15) * 256 + ks * 32 + g * 8);
            acc[0][nf] = mfma16(a0, bq, acc[0][nf]);
            acc[1][nf] = mfma16(a1, bq, acc[1][nf]);
        }
    }
    // capture residual xn = t[row][col] from tS (before qsm overwrite; pre-barrier)
    float res[2][4][4];
#pragma unroll
    for (int mf = 0; mf < 2; ++mf)
#pragma unroll
        for (int r = 0; r < 4; ++r) {
            int row = mf * 16 + g * 4 + r;
            const char* rowp = (const char*)tS + row * 512;
            int sw = (row & 7) << 4;
#pragma unroll
            for (int nf = 0; nf < 4; ++nf) {
                int col = w * 64 + nf * 16 + l15;
                res[mf][nf][r] = (float)*(const bf16*)(rowp + ((col * 2) ^ sw));
            }
        }
    __syncthreads();  // all tS reads done before qsm overwrite
    // phase 2: per-head softmax over d (64 cols), * DH^-0.5, -> qsm LDS (bf16)
#pragma unroll
    for (int mf = 0; mf < 2; ++mf)
#pragma unroll
        for (int hh = 0; hh < 2; ++hh)
#pragma unroll
            for (int r = 0; r < 4; ++r) {
                float mx = -1e30f;
#pragma unroll
                for (int n2 = 0; n2 < 4; ++n2) mx = fmaxf(mx, acc[mf][hh * 4 + n2][r]);
                mx = fmaxf(mx, __shfl_xor(mx, 1));
                mx = fmaxf(mx, __shfl_xor(mx, 2));
                mx = fmaxf(mx, __shfl_xor(mx, 4));
                mx = fmaxf(mx, __shfl_xor(mx, 8));
                float p[4]; float sm = 0.f;
#pragma unroll
                for (int n2 = 0; n2 < 4; ++n2) { p[n2] = __expf(acc[mf][hh * 4 + n2][r] - mx); sm += p[n2]; }
                sm += __shfl_xor(sm, 1);
                sm += __shfl_xor(sm, 2);
                sm += __shfl_xor(sm, 4);
                sm += __shfl_xor(sm, 8);
                float scl = 0.125f / sm;
                int row = mf * 16 + g * 4 + r;
#pragma unroll
                for (int n2 = 0; n2 < 4; ++n2)
                    qsm[row][w * 128 + (hh * 4 + n2) * 16 + l15] = (bf16)(p[n2] * scl);
            }
    __syncthreads();
    // phase 3: out2 = qsm @ M2T  (wave w: 32 rows x cols [w*64, w*64+64) of 256)
    f32x4 acc2[2][4];
#pragma unroll
    for (int mf = 0; mf < 2; ++mf)
#pragma unroll
        for (int nf = 0; nf < 4; ++nf) acc2[mf][nf] = fz;
#pragma unroll
    for (int ks = 0; ks < 16; ++ks) {
        bf16x8 a0 = *(const bf16x8*)(&qsm[l15][ks * 32 + g * 8]);
        bf16x8 a1 = *(const bf16x8*)(&qsm[16 + l15][ks * 32 + g * 8]);
#pragma unroll
        for (int nf = 0; nf < 4; ++nf) {
            bf16x8 bm = *(const bf16x8*)(m2t + (size_t)(b * 256 + w * 64 + nf * 16 + l15) * 512 + ks * 32 + g * 8);
            acc2[0][nf] = mfma16(a0, bm, acc2[0][nf]);
            acc2[1][nf] = mfma16(a1, bm, acc2[1][nf]);
        }
    }
    // phase 4: +bias, rmsnorm over 256 cols, + residual (res regs), write [b][col][pix]
#pragma unroll
    for (int nf = 0; nf < 4; ++nf) {
        float bias = cb[w * 64 + nf * 16 + l15];
#pragma unroll
        for (int mf = 0; mf < 2; ++mf)
#pragma unroll
            for (int r = 0; r < 4; ++r) acc2[mf][nf][r] += bias;
    }
#pragma unroll
    for (int mf = 0; mf < 2; ++mf)
#pragma unroll
        for (int r = 0; r < 4; ++r) {
            float ssq = 0.f;
#pragma unroll
            for (int nf = 0; nf < 4; ++nf) ssq += acc2[mf][nf][r] * acc2[mf][nf][r];
            ssq += __shfl_xor(ssq, 1);
            ssq += __shfl_xor(ssq, 2);
            ssq += __shfl_xor(ssq, 4);
            ssq += __shfl_xor(ssq, 8);
            if (l15 == 0) rowsum[w][mf * 16 + g * 4 + r] = ssq;
        }
    __syncthreads();
#pragma unroll
    for (int mf = 0; mf < 2; ++mf) {
        int pixb = row0 + mf * 16 + g * 4;
        f32x4 scl4;
#pragma unroll
        for (int r = 0; r < 4; ++r) {
            int row = mf * 16 + g * 4 + r;
            float tot = rowsum[0][row] + rowsum[1][row] + rowsum[2][row] + rowsum[3][row];
            scl4[r] = 16.0f / fmaxf(sqrtf(tot), 1e-12f);
        }
#pragma unroll
        for (int nf = 0; nf < 4; ++nf) {
            int col = w * 64 + nf * 16 + l15;
            float gf = gffn[col];
            f32x4 o4;
#pragma unroll
            for (int r = 0; r < 4; ++r)
                o4[r] = acc2[mf][nf][r] * scl4[r] * gf + res[mf][nf][r];
            *(f32x4*)(out + ((size_t)(b * 256 + col)) * N_ + pixb) = o4;
        }
    }
}

extern "C" void kernel_launch(void* const* d_in, const int* in_sizes, int n_in,
                              void* d_out, int out_size, void* d_ws, size_t ws_size,
                              hipStream_t stream) {
    const float* x     = (const float*)d_in[0];
    const float* Wq    = (const float*)d_in[1];
    const float* Wk    = (const float*)d_in[2];
    const float* Wv    = (const float*)d_in[3];
    const float* cw    = (const float*)d_in[4];
    const float* cb    = (const float*)d_in[5];
    const float* gffn  = (const float*)d_in[6];
    const float* gnorm = (const float*)d_in[7];
    char* ws = (char*)d_ws;
    bf16* t    = (bf16*)(ws + T_OFF);
    float* U   = (float*)(ws + U_OFF);
    float* S   = (float*)(ws + S_OFF);
    bf16* m2t  = (bf16*)(ws + M2T_OFF);
    bf16* wqb  = (bf16*)(ws + WQ_OFF);
    bf16* wkb  = (bf16*)(ws + WK_OFF);
    bf16* wvb  = (bf16*)(ws + WV_OFF);
    float* out = (float*)d_out;

    hipMemsetAsync(U, 0, 1048576 + 16384, stream);  // U and S are contiguous
    k_nc<<<704, 256, 0, stream>>>(x, gnorm, t, Wq, Wk, Wv, wqb, wkb, wvb);
    k_kv<<<512, 256, 0, stream>>>(t, wkb, wvb, U, S);
    k_attn_m2<<<256, 256, 0, stream>>>(U, S, cw, m2t);
    k_qout<<<1024, 256, 0, stream>>>(t, wqb, m2t, gffn, cb, out);
}

// Round 8
// 137.866 us; speedup vs baseline: 1.6820x; 1.0231x over previous
//
#include <hip/hip_runtime.h>
#include <hip/hip_bf16.h>

#define B_ 8
#define C_ 256
#define N_ 4096
#define HID_ 512

typedef __bf16 bf16;
typedef bf16 bf16x8 __attribute__((ext_vector_type(8)));
typedef bf16 bf16x4 __attribute__((ext_vector_type(4)));
typedef float f32x4 __attribute__((ext_vector_type(4)));

// ws layout (bytes) — round-3 footprint (20.9 MB, proven within ws_size). Do not grow.
#define T_OFF    0u           // t bf16 [B*N][256]            16 MB   (t == xn, incl. g_norm)
#define U_OFF    16777216u    // U f32  [B][8][64][64]         1 MB
#define S_OFF    17825792u    // S f32  [B][8][64]            16 KB
#define M2T_OFF  17973248u    // M2T bf16 [B][256][512]        2 MB
#define WQ_OFF   20070400u    // Wq bf16 [512][256]          256 KB
#define WK_OFF   20332544u
#define WV_OFF   20594688u

__device__ __forceinline__ f32x4 mfma16(bf16x8 a, bf16x8 b, f32x4 c) {
    return __builtin_amdgcn_mfma_f32_16x16x32_bf16(a, b, c, 0, 0, 0);
}

__device__ __forceinline__ void gload_lds16(const void* g, void* l) {
    __builtin_amdgcn_global_load_lds(
        (const __attribute__((address_space(1))) unsigned int*)g,
        (__attribute__((address_space(3))) unsigned int*)l, 16, 0, 0);
}

// ---- fused: rmsnorm->t (blocks 0..511) + weight cvt fp32->bf16 (blocks 512..703) ----
__global__ void __launch_bounds__(256, 4) k_nc(const float* __restrict__ x,
                                               const float* __restrict__ gnorm,
                                               bf16* __restrict__ t,
                                               const float* __restrict__ wq,
                                               const float* __restrict__ wk,
                                               const float* __restrict__ wv,
                                               bf16* __restrict__ oq,
                                               bf16* __restrict__ ok,
                                               bf16* __restrict__ ov) {
    if (blockIdx.x >= 512) {
        int bb = blockIdx.x - 512;
        int m = bb >> 6;
        const float* src = (m == 0) ? wq : ((m == 1) ? wk : wv);
        bf16* dst = (m == 0) ? oq : ((m == 1) ? ok : ov);
        int i0 = ((bb & 63) * 256 + threadIdx.x) * 8;
        f32x4 a = *(const f32x4*)(src + i0);
        f32x4 b = *(const f32x4*)(src + i0 + 4);
        bf16x8 o;
#pragma unroll
        for (int j = 0; j < 4; ++j) { o[j] = (bf16)a[j]; o[j + 4] = (bf16)b[j]; }
        *(bf16x8*)(dst + i0) = o;
        return;
    }
    __shared__ float part[4][64];
    int b = blockIdx.x >> 6;
    int pix = ((blockIdx.x & 63) << 6) + (threadIdx.x & 63);
    int cq = threadIdx.x >> 6;
    const float* xb = x + (size_t)b * C_ * N_ + (size_t)(cq * 64) * N_ + pix;
    float xv[64];
    float ss = 0.f;
#pragma unroll
    for (int c = 0; c < 64; ++c) { xv[c] = xb[(size_t)c * N_]; ss += xv[c] * xv[c]; }
    part[cq][threadIdx.x & 63] = ss;
    __syncthreads();
    int p = threadIdx.x & 63;
    float tot = part[0][p] + part[1][p] + part[2][p] + part[3][p];
    float s = 16.0f / fmaxf(sqrtf(tot), 1e-12f);
    bf16* tb = t + ((size_t)(b * N_ + pix)) * C_ + cq * 64;
#pragma unroll
    for (int c0 = 0; c0 < 64; c0 += 8) {
        bf16x8 pk;
#pragma unroll
        for (int j = 0; j < 8; ++j)
            pk[j] = (bf16)(xv[c0 + j] * s * gnorm[cq * 64 + c0 + j]);
        *(bf16x8*)(tb + c0) = pk;
    }
}

// ---- fused KV projection + U = exp(K)^T V , S = colsum(exp(K)) ---- (r6-proven)
__global__ void __launch_bounds__(256, 2) k_kv(const bf16* __restrict__ t,
                                               const bf16* __restrict__ wkb,
                                               const bf16* __restrict__ wvb,
                                               float* __restrict__ U,
                                               float* __restrict__ S) {
    __shared__ __align__(16) bf16 tS[64 * 256];   // 32 KB, rows 512B, XOR-swizzled
    __shared__ __align__(16) bf16 ekT[64][72];    // stride 144B = 9*16 (b128-aligned)
    __shared__ __align__(16) bf16 vT[64][72];
    int h = blockIdx.x >> 6;
    int b = (blockIdx.x >> 3) & 7;
    int chunk = blockIdx.x & 7;
    int w = threadIdx.x >> 6;
    int l = threadIdx.x & 63;
    int l15 = l & 15, g = l >> 4;
    int xorm = (l15 & 7) << 4;

    const bf16* wsel = (w < 2) ? wkb : wvb;
    int c0 = (w & 1) * 32;
    bool isk = (w < 2);
    bf16x8 wf[2][8];
#pragma unroll
    for (int nf = 0; nf < 2; ++nf)
#pragma unroll
        for (int ks = 0; ks < 8; ++ks)
            wf[nf][ks] = *(const bf16x8*)(wsel + (size_t)(h * 64 + c0 + nf * 16 + l15) * 256 + ks * 32 + g * 8);

    const f32x4 fz = {0.f, 0.f, 0.f, 0.f};
    f32x4 uacc[4];
#pragma unroll
    for (int df = 0; df < 4; ++df) uacc[df] = fz;
    float sreg = 0.f;

    size_t rowbase = (size_t)b * N_ + chunk * 512;
    for (int tile = 0; tile < 8; ++tile) {
        {
            const char* gt = (const char*)(t + (rowbase + tile * 64) * 256);
#pragma unroll
            for (int it = 0; it < 8; ++it) {
                int o = it * 4096 + w * 1024 + l * 16;
                int src = o ^ (((o >> 9) & 7) << 4);
                gload_lds16(gt + src, (char*)tS + it * 4096 + w * 1024);
            }
        }
        __syncthreads();  // vmcnt drained -> tS ready
        f32x4 acc[4][2];
#pragma unroll
        for (int mf = 0; mf < 4; ++mf) { acc[mf][0] = fz; acc[mf][1] = fz; }
#pragma unroll
        for (int ks = 0; ks < 8; ++ks) {
#pragma unroll
            for (int mf = 0; mf < 4; ++mf) {
                bf16x8 a = *(const bf16x8*)((const char*)tS + (mf * 16 + l15) * 512 + ((ks * 64 + g * 16) ^ xorm));
                acc[mf][0] = mfma16(a, wf[0][ks], acc[mf][0]);
                acc[mf][1] = mfma16(a, wf[1][ks], acc[mf][1]);
            }
        }
        __syncthreads();  // stage-1 tS reads + prev stage-2/S ekT/vT reads done
#pragma unroll
        for (int mf = 0; mf < 4; ++mf)
#pragma unroll
            for (int nf = 0; nf < 2; ++nf) {
                int cc = c0 + nf * 16 + l15;
                int rr = mf * 16 + g * 4;
                bf16x4 pk;
#pragma unroll
                for (int r = 0; r < 4; ++r) {
                    float v = acc[mf][nf][r];
                    pk[r] = (bf16)(isk ? __expf(v) : v);
                }
                if (isk) *(bf16x4*)(&ekT[cc][rr]) = pk;
                else     *(bf16x4*)(&vT[cc][rr]) = pk;
            }
        __syncthreads();  // ekT/vT ready
#pragma unroll
        for (int k2 = 0; k2 < 2; ++k2) {
            bf16x8 bv = *(const bf16x8*)(&vT[w * 16 + l15][k2 * 32 + g * 8]);
#pragma unroll
            for (int df = 0; df < 4; ++df) {
                bf16x8 ae = *(const bf16x8*)(&ekT[df * 16 + l15][k2 * 32 + g * 8]);
                uacc[df] = mfma16(ae, bv, uacc[df]);
            }
        }
        {
#pragma unroll
            for (int i = 0; i < 16; ++i) sreg += (float)ekT[l][w * 16 + i];
        }
    }
    int bh = b * 8 + h;
    float* Ubh = U + (size_t)bh * 4096;
#pragma unroll
    for (int df = 0; df < 4; ++df)
#pragma unroll
        for (int r = 0; r < 4; ++r)
            atomicAdd(Ubh + (df * 16 + g * 4 + r) * 64 + w * 16 + l15, uacc[df][r]);
    atomicAdd(S + bh * 64 + l, sreg);
}

// ---- attn = U/S ; M2T[b][o][h*64+d] = sum_e attn[d][e] * conv_w[o][h*64+e] ----
// grid 256; b = idx&7 -> same-XCD as k_qout's batch-b blocks (m2t[b] left dirty in that L2)
__global__ void __launch_bounds__(256) k_attn_m2(const float* __restrict__ U,
                                                 const float* __restrict__ S,
                                                 const float* __restrict__ cw,
                                                 bf16* __restrict__ m2t) {
    __shared__ float at[16][64];
    int b = blockIdx.x & 7, dq = (blockIdx.x >> 3) & 3, h = blockIdx.x >> 5;
    int tid = threadIdx.x;
    const float* Ub = U + (size_t)(b * 8 + h) * 4096 + dq * 16 * 64;
    const float* Sb = S + (b * 8 + h) * 64 + dq * 16;
    for (int it = 0; it < 4; ++it) {
        int idx = it * 256 + tid;  // 0..1023
        at[idx >> 6][idx & 63] = Ub[idx] / Sb[idx >> 6];
    }
    __syncthreads();
    int o = tid;
    float cwr[64];
#pragma unroll
    for (int e = 0; e < 64; ++e) cwr[e] = cw[(size_t)o * 512 + h * 64 + e];
    bf16* dst = m2t + (size_t)(b * 256 + o) * 512 + h * 64 + dq * 16;
    for (int j0 = 0; j0 < 16; j0 += 8) {
        bf16x8 pk;
#pragma unroll
        for (int j = 0; j < 8; ++j) {
            float a2 = 0.f;
#pragma unroll
            for (int e = 0; e < 64; ++e) a2 += at[j0 + j][e] * cwr[e];
            pk[j] = (bf16)a2;
        }
        *(bf16x8*)(dst + j0) = pk;
    }
}

// ---- fused: q GEMM + per-head softmax + (qsm @ M2T) + bias + rmsnorm + residual ----
// grid 1024; b = blockIdx&7 -> all batch-b blocks on XCD b (m2t[b]+wqb stay L2-resident).
// Epilogue: LDS-transposed, full-128B-line nontemporal stores (fixes 2.2x write amp).
__global__ void __launch_bounds__(256, 4) k_qout(const bf16* __restrict__ t,
                                                 const bf16* __restrict__ wqb,
                                                 const bf16* __restrict__ m2t,
                                                 const float* __restrict__ gffn,
                                                 const float* __restrict__ cb,
                                                 float* __restrict__ out) {
    __shared__ __align__(16) char smem[33792];    // qsm[32][520]bf16 (33280) + rowsum[128]f32 (512)
    bf16 (*qsm)[520] = (bf16(*)[520])smem;        // aliased later as obuf f32[256][33] (33792)
    float* rowsum = (float*)(smem + 33280);
    bf16* tS = (bf16*)smem;
    int b = blockIdx.x & 7;
    int row0 = (blockIdx.x >> 3) << 5;
    int w = threadIdx.x >> 6, l = threadIdx.x & 63;
    int l15 = l & 15, g = l >> 4;
    int xorm = (l15 & 7) << 4;
    const f32x4 fz = {0.f, 0.f, 0.f, 0.f};

    // stage t[32][256] (16KB) swizzled
    {
        const char* gt = (const char*)(t + (size_t)(b * N_ + row0) * 256);
        int tid = threadIdx.x;
#pragma unroll
        for (int it = 0; it < 4; ++it) {
            int o = it * 4096 + tid * 16;
            int src = o ^ (((o >> 9) & 7) << 4);
            gload_lds16(gt + src, (char*)tS + o);
        }
    }
    __syncthreads();  // drains vmcnt -> tS ready

    // phase 1: q = tS @ WqT   (wave w: 32 rows x cols [w*128, w*128+128))
    f32x4 acc[2][8];
#pragma unroll
    for (int mf = 0; mf < 2; ++mf)
#pragma unroll
        for (int nf = 0; nf < 8; ++nf) acc[mf][nf] = fz;
#pragma unroll
    for (int ks = 0; ks < 8; ++ks) {
        bf16x8 a0 = *(const bf16x8*)((const char*)tS + (l15) * 512 + ((ks * 64 + g * 16) ^ xorm));
        bf16x8 a1 = *(const bf16x8*)((const char*)tS + (16 + l15) * 512 + ((ks * 64 + g * 16) ^ xorm));
#pragma unroll
        for (int nf = 0; nf < 8; ++nf) {
            bf16x8 bq = *(const bf16x8*)(wqb + (size_t)(w * 128 + nf * 16 + l15) * 256 + ks * 32 + g * 8);
            acc[0][nf] = mfma16(a0, bq, acc[0][nf]);
            acc[1][nf] = mfma16(a1, bq, acc[1][nf]);
        }
    }
    // capture residual xn = t[row][col] from tS (before qsm overwrite; pre-barrier)
    float res[2][4][4];
#pragma unroll
    for (int mf = 0; mf < 2; ++mf)
#pragma unroll
        for (int r = 0; r < 4; ++r) {
            int row = mf * 16 + g * 4 + r;
            const char* rowp = (const char*)tS + row * 512;
            int sw = (row & 7) << 4;
#pragma unroll
            for (int nf = 0; nf < 4; ++nf) {
                int col = w * 64 + nf * 16 + l15;
                res[mf][nf][r] = (float)*(const bf16*)(rowp + ((col * 2) ^ sw));
            }
        }
    __syncthreads();  // all tS reads done before qsm overwrite
    // phase 2: per-head softmax over d (64 cols), * DH^-0.5, -> qsm LDS (bf16)
#pragma unroll
    for (int mf = 0; mf < 2; ++mf)
#pragma unroll
        for (int hh = 0; hh < 2; ++hh)
#pragma unroll
            for (int r = 0; r < 4; ++r) {
                float mx = -1e30f;
#pragma unroll
                for (int n2 = 0; n2 < 4; ++n2) mx = fmaxf(mx, acc[mf][hh * 4 + n2][r]);
                mx = fmaxf(mx, __shfl_xor(mx, 1));
                mx = fmaxf(mx, __shfl_xor(mx, 2));
                mx = fmaxf(mx, __shfl_xor(mx, 4));
                mx = fmaxf(mx, __shfl_xor(mx, 8));
                float p[4]; float sm = 0.f;
#pragma unroll
                for (int n2 = 0; n2 < 4; ++n2) { p[n2] = __expf(acc[mf][hh * 4 + n2][r] - mx); sm += p[n2]; }
                sm += __shfl_xor(sm, 1);
                sm += __shfl_xor(sm, 2);
                sm += __shfl_xor(sm, 4);
                sm += __shfl_xor(sm, 8);
                float scl = 0.125f / sm;
                int row = mf * 16 + g * 4 + r;
#pragma unroll
                for (int n2 = 0; n2 < 4; ++n2)
                    qsm[row][w * 128 + (hh * 4 + n2) * 16 + l15] = (bf16)(p[n2] * scl);
            }
    __syncthreads();
    // phase 3: out2 = qsm @ M2T  (wave w: 32 rows x cols [w*64, w*64+64) of 256)
    f32x4 acc2[2][4];
#pragma unroll
    for (int mf = 0; mf < 2; ++mf)
#pragma unroll
        for (int nf = 0; nf < 4; ++nf) acc2[mf][nf] = fz;
#pragma unroll
    for (int ks = 0; ks < 16; ++ks) {
        bf16x8 a0 = *(const bf16x8*)(&qsm[l15][ks * 32 + g * 8]);
        bf16x8 a1 = *(const bf16x8*)(&qsm[16 + l15][ks * 32 + g * 8]);
#pragma unroll
        for (int nf = 0; nf < 4; ++nf) {
            bf16x8 bm = *(const bf16x8*)(m2t + (size_t)(b * 256 + w * 64 + nf * 16 + l15) * 512 + ks * 32 + g * 8);
            acc2[0][nf] = mfma16(a0, bm, acc2[0][nf]);
            acc2[1][nf] = mfma16(a1, bm, acc2[1][nf]);
        }
    }
    // phase 4: +bias, rmsnorm over 256 cols
#pragma unroll
    for (int nf = 0; nf < 4; ++nf) {
        float bias = cb[w * 64 + nf * 16 + l15];
#pragma unroll
        for (int mf = 0; mf < 2; ++mf)
#pragma unroll
            for (int r = 0; r < 4; ++r) acc2[mf][nf][r] += bias;
    }
#pragma unroll
    for (int mf = 0; mf < 2; ++mf)
#pragma unroll
        for (int r = 0; r < 4; ++r) {
            float ssq = 0.f;
#pragma unroll
            for (int nf = 0; nf < 4; ++nf) ssq += acc2[mf][nf][r] * acc2[mf][nf][r];
            ssq += __shfl_xor(ssq, 1);
            ssq += __shfl_xor(ssq, 2);
            ssq += __shfl_xor(ssq, 4);
            ssq += __shfl_xor(ssq, 8);
            if (l15 == 0) rowsum[w * 32 + mf * 16 + g * 4 + r] = ssq;
        }
    __syncthreads();  // rowsum complete (also: all waves past phase-3 qsm reads)
    float sclr[2][4];
#pragma unroll
    for (int mf = 0; mf < 2; ++mf)
#pragma unroll
        for (int r = 0; r < 4; ++r) {
            int row = mf * 16 + g * 4 + r;
            float tot = rowsum[row] + rowsum[32 + row] + rowsum[64 + row] + rowsum[96 + row];
            sclr[mf][r] = 16.0f / fmaxf(sqrtf(tot), 1e-12f);
        }
    __syncthreads();  // rowsum/qsm consumed -> smem becomes obuf
    // write o = acc2*scl*gffn + res into obuf[256][33] (stride 33 dw: conflict-free)
    float* obuf = (float*)smem;
#pragma unroll
    for (int nf = 0; nf < 4; ++nf) {
        int col = w * 64 + nf * 16 + l15;
        float gf = gffn[col];
#pragma unroll
        for (int mf = 0; mf < 2; ++mf) {
            int po = col * 33 + mf * 16 + g * 4;
#pragma unroll
            for (int r = 0; r < 4; ++r)
                obuf[po + r] = acc2[mf][nf][r] * sclr[mf][r] * gf + res[mf][nf][r];
        }
    }
    __syncthreads();
    // coalesced read-back: 8 lanes cover one col's 32 floats (128B full line), nontemporal
#pragma unroll
    for (int cc = 0; cc < 8; ++cc) {
        int c = w * 64 + cc * 8 + (l >> 3);
        int j = (l & 7) * 4;
        f32x4 v;
#pragma unroll
        for (int r = 0; r < 4; ++r) v[r] = obuf[c * 33 + j + r];
        __builtin_nontemporal_store(v, (f32x4*)(out + ((size_t)(b * 256 + c)) * N_ + row0 + j));
    }
}

extern "C" void kernel_launch(void* const* d_in, const int* in_sizes, int n_in,
                              void* d_out, int out_size, void* d_ws, size_t ws_size,
                              hipStream_t stream) {
    const float* x     = (const float*)d_in[0];
    const float* Wq    = (const float*)d_in[1];
    const float* Wk    = (const float*)d_in[2];
    const float* Wv    = (const float*)d_in[3];
    const float* cw    = (const float*)d_in[4];
    const float* cb    = (const float*)d_in[5];
    const float* gffn  = (const float*)d_in[6];
    const float* gnorm = (const float*)d_in[7];
    char* ws = (char*)d_ws;
    bf16* t    = (bf16*)(ws + T_OFF);
    float* U   = (float*)(ws + U_OFF);
    float* S   = (float*)(ws + S_OFF);
    bf16* m2t  = (bf16*)(ws + M2T_OFF);
    bf16* wqb  = (bf16*)(ws + WQ_OFF);
    bf16* wkb  = (bf16*)(ws + WK_OFF);
    bf16* wvb  = (bf16*)(ws + WV_OFF);
    float* out = (float*)d_out;

    hipMemsetAsync(U, 0, 1048576 + 16384, stream);  // U and S are contiguous
    k_nc<<<704, 256, 0, stream>>>(x, gnorm, t, Wq, Wk, Wv, wqb, wkb, wvb);
    k_kv<<<512, 256, 0, stream>>>(t, wkb, wvb, U, S);
    k_attn_m2<<<256, 256, 0, stream>>>(U, S, cw, m2t);
    k_qout<<<1024, 256, 0, stream>>>(t, wqb, m2t, gffn, cb, out);
}

// Round 9
// 113.617 us; speedup vs baseline: 2.0410x; 1.2134x over previous
//
#include <hip/hip_runtime.h>
#include <hip/hip_bf16.h>

#define B_ 8
#define C_ 256
#define N_ 4096
#define HID_ 512

typedef __bf16 bf16;
typedef bf16 bf16x8 __attribute__((ext_vector_type(8)));
typedef bf16 bf16x4 __attribute__((ext_vector_type(4)));
typedef float f32x4 __attribute__((ext_vector_type(4)));

// ws layout (bytes) — round-3 footprint (20.9 MB, proven within ws_size). Do not grow.
// wqb/wkb/wvb/m2t are stored FRAGMENT-PACKED: F[p][ks][lane] = M[p*16+(lane&15)][ks*32+(lane>>4)*8+j]
// so every MFMA B-load is 64 lanes x 16B CONTIGUOUS (1 transaction vs 16 scattered).
#define T_OFF    0u           // t bf16 [B*N][256]            16 MB   (t == xn, incl. g_norm)
#define U_OFF    16777216u    // U f32  [B][8][64][64]         1 MB
#define S_OFF    17825792u    // S f32  [B][8][64]            16 KB
#define M2T_OFF  17973248u    // M2T bf16 packed [B][16p][16ks][64][8]  2 MB
#define WQ_OFF   20070400u    // Wq bf16 packed [32p][8ks][64][8]     256 KB
#define WK_OFF   20332544u
#define WV_OFF   20594688u

__device__ __forceinline__ f32x4 mfma16(bf16x8 a, bf16x8 b, f32x4 c) {
    return __builtin_amdgcn_mfma_f32_16x16x32_bf16(a, b, c, 0, 0, 0);
}

__device__ __forceinline__ void gload_lds16(const void* g, void* l) {
    __builtin_amdgcn_global_load_lds(
        (const __attribute__((address_space(1))) unsigned int*)g,
        (__attribute__((address_space(3))) unsigned int*)l, 16, 0, 0);
}

// ---- fused: rmsnorm->t (blocks 0..511) + weight cvt fp32->bf16 PACKED (512..703) ----
__global__ void __launch_bounds__(256, 4) k_nc(const float* __restrict__ x,
                                               const float* __restrict__ gnorm,
                                               bf16* __restrict__ t,
                                               const float* __restrict__ wq,
                                               const float* __restrict__ wk,
                                               const float* __restrict__ wv,
                                               bf16* __restrict__ oq,
                                               bf16* __restrict__ ok,
                                               bf16* __restrict__ ov) {
    if (blockIdx.x >= 512) {
        int bb = blockIdx.x - 512;
        int m = bb >> 6;
        const float* src = (m == 0) ? wq : ((m == 1) ? wk : wv);
        bf16* dst = (m == 0) ? oq : ((m == 1) ? ok : ov);
        int tid = threadIdx.x;
        int i0 = ((bb & 63) * 256 + tid) * 8;   // 8 consecutive k of one row
        f32x4 a = *(const f32x4*)(src + i0);
        f32x4 b2 = *(const f32x4*)(src + i0 + 4);
        bf16x8 o;
#pragma unroll
        for (int j = 0; j < 4; ++j) { o[j] = (bf16)a[j]; o[j + 4] = (bf16)b2[j]; }
        // packed dest: row=(bb&63)*8+(tid>>5), k0=(tid&31)*8
        int row = (bb & 63) * 8 + (tid >> 5);
        int k0 = (tid & 31) * 8;
        int p = row >> 4, l15 = row & 15;
        int ks = k0 >> 5, g = (k0 >> 3) & 3;
        *(bf16x8*)(dst + ((size_t)((p * 8 + ks) * 64 + g * 16 + l15)) * 8) = o;
        return;
    }
    __shared__ float part[4][64];
    int b = blockIdx.x >> 6;
    int pix = ((blockIdx.x & 63) << 6) + (threadIdx.x & 63);
    int cq = threadIdx.x >> 6;
    const float* xb = x + (size_t)b * C_ * N_ + (size_t)(cq * 64) * N_ + pix;
    float xv[64];
    float ss = 0.f;
#pragma unroll
    for (int c = 0; c < 64; ++c) { xv[c] = xb[(size_t)c * N_]; ss += xv[c] * xv[c]; }
    part[cq][threadIdx.x & 63] = ss;
    __syncthreads();
    int p = threadIdx.x & 63;
    float tot = part[0][p] + part[1][p] + part[2][p] + part[3][p];
    float s = 16.0f / fmaxf(sqrtf(tot), 1e-12f);
    bf16* tb = t + ((size_t)(b * N_ + pix)) * C_ + cq * 64;
#pragma unroll
    for (int c0 = 0; c0 < 64; c0 += 8) {
        bf16x8 pk;
#pragma unroll
        for (int j = 0; j < 8; ++j)
            pk[j] = (bf16)(xv[c0 + j] * s * gnorm[cq * 64 + c0 + j]);
        *(bf16x8*)(tb + c0) = pk;
    }
}

// ---- fused KV projection + U = exp(K)^T V , S = colsum(exp(K)) ---- (r6-proven)
// Weights read from PACKED layout: one 1KB-contiguous load per (nf,ks).
__global__ void __launch_bounds__(256, 2) k_kv(const bf16* __restrict__ t,
                                               const bf16* __restrict__ wkb,
                                               const bf16* __restrict__ wvb,
                                               float* __restrict__ U,
                                               float* __restrict__ S) {
    __shared__ __align__(16) bf16 tS[64 * 256];   // 32 KB, rows 512B, XOR-swizzled
    __shared__ __align__(16) bf16 ekT[64][72];    // stride 144B = 9*16 (b128-aligned)
    __shared__ __align__(16) bf16 vT[64][72];
    int h = blockIdx.x >> 6;
    int b = (blockIdx.x >> 3) & 7;
    int chunk = blockIdx.x & 7;
    int w = threadIdx.x >> 6;
    int l = threadIdx.x & 63;
    int l15 = l & 15, g = l >> 4;
    int xorm = (l15 & 7) << 4;

    const bf16* wsel = (w < 2) ? wkb : wvb;
    int c0 = (w & 1) * 32;
    bool isk = (w < 2);
    bf16x8 wf[2][8];
#pragma unroll
    for (int nf = 0; nf < 2; ++nf) {
        int pp = h * 4 + (w & 1) * 2 + nf;   // 16-row panel index
#pragma unroll
        for (int ks = 0; ks < 8; ++ks)
            wf[nf][ks] = *(const bf16x8*)(wsel + ((size_t)((pp * 8 + ks) * 64 + l)) * 8);
    }

    const f32x4 fz = {0.f, 0.f, 0.f, 0.f};
    f32x4 uacc[4];
#pragma unroll
    for (int df = 0; df < 4; ++df) uacc[df] = fz;
    float sreg = 0.f;

    size_t rowbase = (size_t)b * N_ + chunk * 512;
    for (int tile = 0; tile < 8; ++tile) {
        {
            const char* gt = (const char*)(t + (rowbase + tile * 64) * 256);
#pragma unroll
            for (int it = 0; it < 8; ++it) {
                int o = it * 4096 + w * 1024 + l * 16;
                int src = o ^ (((o >> 9) & 7) << 4);
                gload_lds16(gt + src, (char*)tS + it * 4096 + w * 1024);
            }
        }
        __syncthreads();  // vmcnt drained -> tS ready
        f32x4 acc[4][2];
#pragma unroll
        for (int mf = 0; mf < 4; ++mf) { acc[mf][0] = fz; acc[mf][1] = fz; }
#pragma unroll
        for (int ks = 0; ks < 8; ++ks) {
#pragma unroll
            for (int mf = 0; mf < 4; ++mf) {
                bf16x8 a = *(const bf16x8*)((const char*)tS + (mf * 16 + l15) * 512 + ((ks * 64 + g * 16) ^ xorm));
                acc[mf][0] = mfma16(a, wf[0][ks], acc[mf][0]);
                acc[mf][1] = mfma16(a, wf[1][ks], acc[mf][1]);
            }
        }
        __syncthreads();  // stage-1 tS reads + prev stage-2/S ekT/vT reads done
#pragma unroll
        for (int mf = 0; mf < 4; ++mf)
#pragma unroll
            for (int nf = 0; nf < 2; ++nf) {
                int cc = c0 + nf * 16 + l15;
                int rr = mf * 16 + g * 4;
                bf16x4 pk;
#pragma unroll
                for (int r = 0; r < 4; ++r) {
                    float v = acc[mf][nf][r];
                    pk[r] = (bf16)(isk ? __expf(v) : v);
                }
                if (isk) *(bf16x4*)(&ekT[cc][rr]) = pk;
                else     *(bf16x4*)(&vT[cc][rr]) = pk;
            }
        __syncthreads();  // ekT/vT ready
#pragma unroll
        for (int k2 = 0; k2 < 2; ++k2) {
            bf16x8 bv = *(const bf16x8*)(&vT[w * 16 + l15][k2 * 32 + g * 8]);
#pragma unroll
            for (int df = 0; df < 4; ++df) {
                bf16x8 ae = *(const bf16x8*)(&ekT[df * 16 + l15][k2 * 32 + g * 8]);
                uacc[df] = mfma16(ae, bv, uacc[df]);
            }
        }
        {
#pragma unroll
            for (int i = 0; i < 16; ++i) sreg += (float)ekT[l][w * 16 + i];
        }
    }
    int bh = b * 8 + h;
    float* Ubh = U + (size_t)bh * 4096;
#pragma unroll
    for (int df = 0; df < 4; ++df)
#pragma unroll
        for (int r = 0; r < 4; ++r)
            atomicAdd(Ubh + (df * 16 + g * 4 + r) * 64 + w * 16 + l15, uacc[df][r]);
    atomicAdd(S + bh * 64 + l, sreg);
}

// ---- attn = U/S ; M2 packed-fragment output ----
// grid 256; b = idx&7 -> same-XCD as k_qout's batch-b blocks
__global__ void __launch_bounds__(256) k_attn_m2(const float* __restrict__ U,
                                                 const float* __restrict__ S,
                                                 const float* __restrict__ cw,
                                                 bf16* __restrict__ m2t) {
    __shared__ float at[16][64];
    int b = blockIdx.x & 7, dq = (blockIdx.x >> 3) & 3, h = blockIdx.x >> 5;
    int tid = threadIdx.x;
    const float* Ub = U + (size_t)(b * 8 + h) * 4096 + dq * 16 * 64;
    const float* Sb = S + (b * 8 + h) * 64 + dq * 16;
    for (int it = 0; it < 4; ++it) {
        int idx = it * 256 + tid;  // 0..1023
        at[idx >> 6][idx & 63] = Ub[idx] / Sb[idx >> 6];
    }
    __syncthreads();
    int o = tid;
    float cwr[64];
#pragma unroll
    for (int e = 0; e < 64; ++e) cwr[e] = cw[(size_t)o * 512 + h * 64 + e];
    // packed store: M2[o][k], k = h*64 + dq*16 + j0 + j
    bf16* mb = m2t + (size_t)b * 131072;
    int pp = o >> 4, l15o = o & 15;
#pragma unroll
    for (int j0 = 0; j0 < 16; j0 += 8) {
        bf16x8 pk;
#pragma unroll
        for (int j = 0; j < 8; ++j) {
            float a2 = 0.f;
#pragma unroll
            for (int e = 0; e < 64; ++e) a2 += at[dq == dq ? (j0 + j) : 0][e] * cwr[e];
            pk[j] = (bf16)a2;
        }
        int kk = dq * 16 + j0;                 // k within head, 0..56
        int ksg = h * 2 + (kk >> 5);           // global ks (0..15)
        int gg = (kk >> 3) & 3;
        *(bf16x8*)(mb + ((size_t)((pp * 16 + ksg) * 64 + gg * 16 + l15o)) * 8) = pk;
    }
}

// ---- fused: q GEMM + per-head softmax + (qsm @ M2T) + bias + rmsnorm + residual ----
// grid 1024; b = blockIdx&7. B-operands (wqb, m2t) read from PACKED layouts:
// each (nf,ks) load = 64 lanes x 16B contiguous (1 transaction vs 16).
__global__ void __launch_bounds__(256, 4) k_qout(const bf16* __restrict__ t,
                                                 const bf16* __restrict__ wqb,
                                                 const bf16* __restrict__ m2t,
                                                 const float* __restrict__ gffn,
                                                 const float* __restrict__ cb,
                                                 float* __restrict__ out) {
    __shared__ __align__(16) char smem[33792];    // qsm[32][520]bf16 (33280) + rowsum[128]f32 (512)
    bf16 (*qsm)[520] = (bf16(*)[520])smem;        // aliased later as obuf f32[256][33] (33792)
    float* rowsum = (float*)(smem + 33280);
    bf16* tS = (bf16*)smem;
    int b = blockIdx.x & 7;
    int row0 = (blockIdx.x >> 3) << 5;
    int w = threadIdx.x >> 6, l = threadIdx.x & 63;
    int l15 = l & 15, g = l >> 4;
    int xorm = (l15 & 7) << 4;
    const f32x4 fz = {0.f, 0.f, 0.f, 0.f};

    // stage t[32][256] (16KB) swizzled
    {
        const char* gt = (const char*)(t + (size_t)(b * N_ + row0) * 256);
        int tid = threadIdx.x;
#pragma unroll
        for (int it = 0; it < 4; ++it) {
            int o = it * 4096 + tid * 16;
            int src = o ^ (((o >> 9) & 7) << 4);
            gload_lds16(gt + src, (char*)tS + o);
        }
    }
    __syncthreads();  // drains vmcnt -> tS ready

    // phase 1: q = tS @ WqT   (wave w: 32 rows x cols [w*128, w*128+128))
    f32x4 acc[2][8];
#pragma unroll
    for (int mf = 0; mf < 2; ++mf)
#pragma unroll
        for (int nf = 0; nf < 8; ++nf) acc[mf][nf] = fz;
#pragma unroll
    for (int ks = 0; ks < 8; ++ks) {
        bf16x8 a0 = *(const bf16x8*)((const char*)tS + (l15) * 512 + ((ks * 64 + g * 16) ^ xorm));
        bf16x8 a1 = *(const bf16x8*)((const char*)tS + (16 + l15) * 512 + ((ks * 64 + g * 16) ^ xorm));
#pragma unroll
        for (int nf = 0; nf < 8; ++nf) {
            bf16x8 bq = *(const bf16x8*)(wqb + ((size_t)(((w * 8 + nf) * 8 + ks) * 64 + l)) * 8);
            acc[0][nf] = mfma16(a0, bq, acc[0][nf]);
            acc[1][nf] = mfma16(a1, bq, acc[1][nf]);
        }
    }
    // capture residual xn = t[row][col] from tS (before qsm overwrite; pre-barrier)
    float res[2][4][4];
#pragma unroll
    for (int mf = 0; mf < 2; ++mf)
#pragma unroll
        for (int r = 0; r < 4; ++r) {
            int row = mf * 16 + g * 4 + r;
            const char* rowp = (const char*)tS + row * 512;
            int sw = (row & 7) << 4;
#pragma unroll
            for (int nf = 0; nf < 4; ++nf) {
                int col = w * 64 + nf * 16 + l15;
                res[mf][nf][r] = (float)*(const bf16*)(rowp + ((col * 2) ^ sw));
            }
        }
    __syncthreads();  // all tS reads done before qsm overwrite
    // phase 2: per-head softmax over d (64 cols), * DH^-0.5, -> qsm LDS (bf16)
#pragma unroll
    for (int mf = 0; mf < 2; ++mf)
#pragma unroll
        for (int hh = 0; hh < 2; ++hh)
#pragma unroll
            for (int r = 0; r < 4; ++r) {
                float mx = -1e30f;
#pragma unroll
                for (int n2 = 0; n2 < 4; ++n2) mx = fmaxf(mx, acc[mf][hh * 4 + n2][r]);
                mx = fmaxf(mx, __shfl_xor(mx, 1));
                mx = fmaxf(mx, __shfl_xor(mx, 2));
                mx = fmaxf(mx, __shfl_xor(mx, 4));
                mx = fmaxf(mx, __shfl_xor(mx, 8));
                float p[4]; float sm = 0.f;
#pragma unroll
                for (int n2 = 0; n2 < 4; ++n2) { p[n2] = __expf(acc[mf][hh * 4 + n2][r] - mx); sm += p[n2]; }
                sm += __shfl_xor(sm, 1);
                sm += __shfl_xor(sm, 2);
                sm += __shfl_xor(sm, 4);
                sm += __shfl_xor(sm, 8);
                float scl = 0.125f / sm;
                int row = mf * 16 + g * 4 + r;
#pragma unroll
                for (int n2 = 0; n2 < 4; ++n2)
                    qsm[row][w * 128 + (hh * 4 + n2) * 16 + l15] = (bf16)(p[n2] * scl);
            }
    __syncthreads();
    // phase 3: out2 = qsm @ M2T  (wave w: 32 rows x cols [w*64, w*64+64) of 256)
    f32x4 acc2[2][4];
#pragma unroll
    for (int mf = 0; mf < 2; ++mf)
#pragma unroll
        for (int nf = 0; nf < 4; ++nf) acc2[mf][nf] = fz;
    const bf16* mb = m2t + (size_t)b * 131072;
#pragma unroll
    for (int ks = 0; ks < 16; ++ks) {
        bf16x8 a0 = *(const bf16x8*)(&qsm[l15][ks * 32 + g * 8]);
        bf16x8 a1 = *(const bf16x8*)(&qsm[16 + l15][ks * 32 + g * 8]);
#pragma unroll
        for (int nf = 0; nf < 4; ++nf) {
            bf16x8 bm = *(const bf16x8*)(mb + ((size_t)(((w * 4 + nf) * 16 + ks) * 64 + l)) * 8);
            acc2[0][nf] = mfma16(a0, bm, acc2[0][nf]);
            acc2[1][nf] = mfma16(a1, bm, acc2[1][nf]);
        }
    }
    // phase 4: +bias, rmsnorm over 256 cols
#pragma unroll
    for (int nf = 0; nf < 4; ++nf) {
        float bias = cb[w * 64 + nf * 16 + l15];
#pragma unroll
        for (int mf = 0; mf < 2; ++mf)
#pragma unroll
            for (int r = 0; r < 4; ++r) acc2[mf][nf][r] += bias;
    }
#pragma unroll
    for (int mf = 0; mf < 2; ++mf)
#pragma unroll
        for (int r = 0; r < 4; ++r) {
            float ssq = 0.f;
#pragma unroll
            for (int nf = 0; nf < 4; ++nf) ssq += acc2[mf][nf][r] * acc2[mf][nf][r];
            ssq += __shfl_xor(ssq, 1);
            ssq += __shfl_xor(ssq, 2);
            ssq += __shfl_xor(ssq, 4);
            ssq += __shfl_xor(ssq, 8);
            if (l15 == 0) rowsum[w * 32 + mf * 16 + g * 4 + r] = ssq;
        }
    __syncthreads();  // rowsum complete (also: all waves past phase-3 qsm reads)
    float sclr[2][4];
#pragma unroll
    for (int mf = 0; mf < 2; ++mf)
#pragma unroll
        for (int r = 0; r < 4; ++r) {
            int row = mf * 16 + g * 4 + r;
            float tot = rowsum[row] + rowsum[32 + row] + rowsum[64 + row] + rowsum[96 + row];
            sclr[mf][r] = 16.0f / fmaxf(sqrtf(tot), 1e-12f);
        }
    __syncthreads();  // rowsum/qsm consumed -> smem becomes obuf
    // write o = acc2*scl*gffn + res into obuf[256][33] (stride 33 dw: conflict-free)
    float* obuf = (float*)smem;
#pragma unroll
    for (int nf = 0; nf < 4; ++nf) {
        int col = w * 64 + nf * 16 + l15;
        float gf = gffn[col];
#pragma unroll
        for (int mf = 0; mf < 2; ++mf) {
            int po = col * 33 + mf * 16 + g * 4;
#pragma unroll
            for (int r = 0; r < 4; ++r)
                obuf[po + r] = acc2[mf][nf][r] * sclr[mf][r] * gf + res[mf][nf][r];
        }
    }
    __syncthreads();
    // coalesced read-back: 8 lanes cover one col's 32 floats (128B full line), nontemporal
#pragma unroll
    for (int cc = 0; cc < 8; ++cc) {
        int c = w * 64 + cc * 8 + (l >> 3);
        int j = (l & 7) * 4;
        f32x4 v;
#pragma unroll
        for (int r = 0; r < 4; ++r) v[r] = obuf[c * 33 + j + r];
        __builtin_nontemporal_store(v, (f32x4*)(out + ((size_t)(b * 256 + c)) * N_ + row0 + j));
    }
}

extern "C" void kernel_launch(void* const* d_in, const int* in_sizes, int n_in,
                              void* d_out, int out_size, void* d_ws, size_t ws_size,
                              hipStream_t stream) {
    const float* x     = (const float*)d_in[0];
    const float* Wq    = (const float*)d_in[1];
    const float* Wk    = (const float*)d_in[2];
    const float* Wv    = (const float*)d_in[3];
    const float* cw    = (const float*)d_in[4];
    const float* cb    = (const float*)d_in[5];
    const float* gffn  = (const float*)d_in[6];
    const float* gnorm = (const float*)d_in[7];
    char* ws = (char*)d_ws;
    bf16* t    = (bf16*)(ws + T_OFF);
    float* U   = (float*)(ws + U_OFF);
    float* S   = (float*)(ws + S_OFF);
    bf16* m2t  = (bf16*)(ws + M2T_OFF);
    bf16* wqb  = (bf16*)(ws + WQ_OFF);
    bf16* wkb  = (bf16*)(ws + WK_OFF);
    bf16* wvb  = (bf16*)(ws + WV_OFF);
    float* out = (float*)d_out;

    hipMemsetAsync(U, 0, 1048576 + 16384, stream);  // U and S are contiguous
    k_nc<<<704, 256, 0, stream>>>(x, gnorm, t, Wq, Wk, Wv, wqb, wkb, wvb);
    k_kv<<<512, 256, 0, stream>>>(t, wkb, wvb, U, S);
    k_attn_m2<<<256, 256, 0, stream>>>(U, S, cw, m2t);
    k_qout<<<1024, 256, 0, stream>>>(t, wqb, m2t, gffn, cb, out);
}

// Round 10
// 97.362 us; speedup vs baseline: 2.3818x; 1.1670x over previous
//
#include <hip/hip_runtime.h>
#include <hip/hip_bf16.h>

#define B_ 8
#define C_ 256
#define N_ 4096
#define HID_ 512

typedef __bf16 bf16;
typedef bf16 bf16x8 __attribute__((ext_vector_type(8)));
typedef bf16 bf16x4 __attribute__((ext_vector_type(4)));
typedef float f32x4 __attribute__((ext_vector_type(4)));

// ws layout (bytes) — round-3 footprint (20.9 MB, proven within ws_size). Do not grow.
// wqb/wkb/wvb/m2t are stored FRAGMENT-PACKED: F[p][ks][lane] = M[p*16+(lane&15)][ks*32+(lane>>4)*8+j]
// so every MFMA B-load is 64 lanes x 16B CONTIGUOUS (1 transaction vs 16 scattered).
#define T_OFF    0u           // t bf16 [B*N][256]            16 MB   (t == xn, incl. g_norm)
#define U_OFF    16777216u    // U f32  [B][8][64][64]         1 MB
#define S_OFF    17825792u    // S f32  [B][8][64]            16 KB
#define M2T_OFF  17973248u    // M2T bf16 packed [B][16p][16ks][64][8]  2 MB
#define WQ_OFF   20070400u    // Wq bf16 packed [32p][8ks][64][8]     256 KB
#define WK_OFF   20332544u
#define WV_OFF   20594688u

__device__ __forceinline__ f32x4 mfma16(bf16x8 a, bf16x8 b, f32x4 c) {
    return __builtin_amdgcn_mfma_f32_16x16x32_bf16(a, b, c, 0, 0, 0);
}

__device__ __forceinline__ void gload_lds16(const void* g, void* l) {
    __builtin_amdgcn_global_load_lds(
        (const __attribute__((address_space(1))) unsigned int*)g,
        (__attribute__((address_space(3))) unsigned int*)l, 16, 0, 0);
}

// ---- fused: rmsnorm->t (blocks 0..511) + weight cvt fp32->bf16 PACKED (512..703) ----
__global__ void __launch_bounds__(256, 4) k_nc(const float* __restrict__ x,
                                               const float* __restrict__ gnorm,
                                               bf16* __restrict__ t,
                                               const float* __restrict__ wq,
                                               const float* __restrict__ wk,
                                               const float* __restrict__ wv,
                                               bf16* __restrict__ oq,
                                               bf16* __restrict__ ok,
                                               bf16* __restrict__ ov) {
    if (blockIdx.x >= 512) {
        int bb = blockIdx.x - 512;
        int m = bb >> 6;
        const float* src = (m == 0) ? wq : ((m == 1) ? wk : wv);
        bf16* dst = (m == 0) ? oq : ((m == 1) ? ok : ov);
        int tid = threadIdx.x;
        int i0 = ((bb & 63) * 256 + tid) * 8;   // 8 consecutive k of one row
        f32x4 a = *(const f32x4*)(src + i0);
        f32x4 b2 = *(const f32x4*)(src + i0 + 4);
        bf16x8 o;
#pragma unroll
        for (int j = 0; j < 4; ++j) { o[j] = (bf16)a[j]; o[j + 4] = (bf16)b2[j]; }
        // packed dest: row=(bb&63)*8+(tid>>5), k0=(tid&31)*8
        int row = (bb & 63) * 8 + (tid >> 5);
        int k0 = (tid & 31) * 8;
        int p = row >> 4, l15 = row & 15;
        int ks = k0 >> 5, g = (k0 >> 3) & 3;
        *(bf16x8*)(dst + ((size_t)((p * 8 + ks) * 64 + g * 16 + l15)) * 8) = o;
        return;
    }
    __shared__ float part[4][64];
    int b = blockIdx.x >> 6;
    int pix = ((blockIdx.x & 63) << 6) + (threadIdx.x & 63);
    int cq = threadIdx.x >> 6;
    const float* xb = x + (size_t)b * C_ * N_ + (size_t)(cq * 64) * N_ + pix;
    float xv[64];
    float ss = 0.f;
#pragma unroll
    for (int c = 0; c < 64; ++c) { xv[c] = xb[(size_t)c * N_]; ss += xv[c] * xv[c]; }
    part[cq][threadIdx.x & 63] = ss;
    __syncthreads();
    int p = threadIdx.x & 63;
    float tot = part[0][p] + part[1][p] + part[2][p] + part[3][p];
    float s = 16.0f / fmaxf(sqrtf(tot), 1e-12f);
    bf16* tb = t + ((size_t)(b * N_ + pix)) * C_ + cq * 64;
#pragma unroll
    for (int c0 = 0; c0 < 64; c0 += 8) {
        bf16x8 pk;
#pragma unroll
        for (int j = 0; j < 8; ++j)
            pk[j] = (bf16)(xv[c0 + j] * s * gnorm[cq * 64 + c0 + j]);
        *(bf16x8*)(tb + c0) = pk;
    }
}

// ---- fused KV projection + U = exp(K)^T V , S = colsum(exp(K)) ---- (r6-proven)
// Weights read from PACKED layout: one 1KB-contiguous load per (nf,ks).
__global__ void __launch_bounds__(256, 2) k_kv(const bf16* __restrict__ t,
                                               const bf16* __restrict__ wkb,
                                               const bf16* __restrict__ wvb,
                                               float* __restrict__ U,
                                               float* __restrict__ S) {
    __shared__ __align__(16) bf16 tS[64 * 256];   // 32 KB, rows 512B, XOR-swizzled
    __shared__ __align__(16) bf16 ekT[64][72];    // stride 144B = 9*16 (b128-aligned)
    __shared__ __align__(16) bf16 vT[64][72];
    int h = blockIdx.x >> 6;
    int b = (blockIdx.x >> 3) & 7;
    int chunk = blockIdx.x & 7;
    int w = threadIdx.x >> 6;
    int l = threadIdx.x & 63;
    int l15 = l & 15, g = l >> 4;
    int xorm = (l15 & 7) << 4;

    const bf16* wsel = (w < 2) ? wkb : wvb;
    int c0 = (w & 1) * 32;
    bool isk = (w < 2);
    bf16x8 wf[2][8];
#pragma unroll
    for (int nf = 0; nf < 2; ++nf) {
        int pp = h * 4 + (w & 1) * 2 + nf;   // 16-row panel index
#pragma unroll
        for (int ks = 0; ks < 8; ++ks)
            wf[nf][ks] = *(const bf16x8*)(wsel + ((size_t)((pp * 8 + ks) * 64 + l)) * 8);
    }

    const f32x4 fz = {0.f, 0.f, 0.f, 0.f};
    f32x4 uacc[4];
#pragma unroll
    for (int df = 0; df < 4; ++df) uacc[df] = fz;
    float sreg = 0.f;

    size_t rowbase = (size_t)b * N_ + chunk * 512;
    for (int tile = 0; tile < 8; ++tile) {
        {
            const char* gt = (const char*)(t + (rowbase + tile * 64) * 256);
#pragma unroll
            for (int it = 0; it < 8; ++it) {
                int o = it * 4096 + w * 1024 + l * 16;
                int src = o ^ (((o >> 9) & 7) << 4);
                gload_lds16(gt + src, (char*)tS + it * 4096 + w * 1024);
            }
        }
        __syncthreads();  // vmcnt drained -> tS ready
        f32x4 acc[4][2];
#pragma unroll
        for (int mf = 0; mf < 4; ++mf) { acc[mf][0] = fz; acc[mf][1] = fz; }
#pragma unroll
        for (int ks = 0; ks < 8; ++ks) {
#pragma unroll
            for (int mf = 0; mf < 4; ++mf) {
                bf16x8 a = *(const bf16x8*)((const char*)tS + (mf * 16 + l15) * 512 + ((ks * 64 + g * 16) ^ xorm));
                acc[mf][0] = mfma16(a, wf[0][ks], acc[mf][0]);
                acc[mf][1] = mfma16(a, wf[1][ks], acc[mf][1]);
            }
        }
        __syncthreads();  // stage-1 tS reads + prev stage-2/S ekT/vT reads done
#pragma unroll
        for (int mf = 0; mf < 4; ++mf)
#pragma unroll
            for (int nf = 0; nf < 2; ++nf) {
                int cc = c0 + nf * 16 + l15;
                int rr = mf * 16 + g * 4;
                bf16x4 pk;
#pragma unroll
                for (int r = 0; r < 4; ++r) {
                    float v = acc[mf][nf][r];
                    pk[r] = (bf16)(isk ? __expf(v) : v);
                }
                if (isk) *(bf16x4*)(&ekT[cc][rr]) = pk;
                else     *(bf16x4*)(&vT[cc][rr]) = pk;
            }
        __syncthreads();  // ekT/vT ready
#pragma unroll
        for (int k2 = 0; k2 < 2; ++k2) {
            bf16x8 bv = *(const bf16x8*)(&vT[w * 16 + l15][k2 * 32 + g * 8]);
#pragma unroll
            for (int df = 0; df < 4; ++df) {
                bf16x8 ae = *(const bf16x8*)(&ekT[df * 16 + l15][k2 * 32 + g * 8]);
                uacc[df] = mfma16(ae, bv, uacc[df]);
            }
        }
        {
#pragma unroll
            for (int i = 0; i < 16; ++i) sreg += (float)ekT[l][w * 16 + i];
        }
    }
    int bh = b * 8 + h;
    float* Ubh = U + (size_t)bh * 4096;
#pragma unroll
    for (int df = 0; df < 4; ++df)
#pragma unroll
        for (int r = 0; r < 4; ++r)
            atomicAdd(Ubh + (df * 16 + g * 4 + r) * 64 + w * 16 + l15, uacc[df][r]);
    atomicAdd(S + bh * 64 + l, sreg);
}

// ---- attn = U/S ; M2 packed-fragment output ----
// grid 256; b = idx&7 -> same-XCD as k_qout's batch-b blocks
__global__ void __launch_bounds__(256) k_attn_m2(const float* __restrict__ U,
                                                 const float* __restrict__ S,
                                                 const float* __restrict__ cw,
                                                 bf16* __restrict__ m2t) {
    __shared__ float at[16][64];
    int b = blockIdx.x & 7, dq = (blockIdx.x >> 3) & 3, h = blockIdx.x >> 5;
    int tid = threadIdx.x;
    const float* Ub = U + (size_t)(b * 8 + h) * 4096 + dq * 16 * 64;
    const float* Sb = S + (b * 8 + h) * 64 + dq * 16;
    for (int it = 0; it < 4; ++it) {
        int idx = it * 256 + tid;  // 0..1023
        at[idx >> 6][idx & 63] = Ub[idx] / Sb[idx >> 6];
    }
    __syncthreads();
    int o = tid;
    float cwr[64];
#pragma unroll
    for (int e = 0; e < 64; ++e) cwr[e] = cw[(size_t)o * 512 + h * 64 + e];
    // packed store: M2[o][k], k = h*64 + dq*16 + j0 + j
    bf16* mb = m2t + (size_t)b * 131072;
    int pp = o >> 4, l15o = o & 15;
#pragma unroll
    for (int j0 = 0; j0 < 16; j0 += 8) {
        bf16x8 pk;
#pragma unroll
        for (int j = 0; j < 8; ++j) {
            float a2 = 0.f;
#pragma unroll
            for (int e = 0; e < 64; ++e) a2 += at[j0 + j][e] * cwr[e];
            pk[j] = (bf16)a2;
        }
        int kk = dq * 16 + j0;                 // k within head, 0..56
        int ksg = h * 2 + (kk >> 5);           // global ks (0..15)
        int gg = (kk >> 3) & 3;
        *(bf16x8*)(mb + ((size_t)((pp * 16 + ksg) * 64 + gg * 16 + l15o)) * 8) = pk;
    }
}

// ---- fused: q GEMM + per-head softmax + (qsm @ M2T) + bias + rmsnorm + residual ----
// grid 512 = b(8) x rowtile(64 of 64 rows); 512 threads (8 waves), 2 blocks/CU.
// Wave w owns q-cols [w*64,w*64+64) == head w (softmax is wave-local) and
// out-cols [w*32,w*32+32). Each block streams whole wqb+m2t[b] once for 64 rows
// (was: once per 32 rows) -> L2 B-traffic halved. LDS one 65KB region aliased
// tS(32K) -> qsm[64][520] -> obuf[256][65]; residual re-read from t (L2-hot) in
// epilogue instead of register capture (keeps VGPR<=128 for 4 waves/SIMD).
__global__ void __launch_bounds__(512, 4) k_qout(const bf16* __restrict__ t,
                                                 const bf16* __restrict__ wqb,
                                                 const bf16* __restrict__ m2t,
                                                 const float* __restrict__ gffn,
                                                 const float* __restrict__ cb,
                                                 float* __restrict__ out) {
    __shared__ __align__(16) char smem[66560 + 2048];  // qsm/tS/obuf (66560) + rowsum[8][64]
    bf16 (*qsm)[520] = (bf16(*)[520])smem;
    float* rowsum = (float*)(smem + 66560);
    bf16* tS = (bf16*)smem;
    int b = blockIdx.x & 7;
    int row0 = (blockIdx.x >> 3) << 6;
    int tid = threadIdx.x;
    int w = tid >> 6, l = tid & 63;
    int l15 = l & 15, g = l >> 4;
    int xorm = (l15 & 7) << 4;
    const f32x4 fz = {0.f, 0.f, 0.f, 0.f};

    // stage t[64][256] (32KB) swizzled
    {
        const char* gt = (const char*)(t + (size_t)(b * N_ + row0) * 256);
#pragma unroll
        for (int it = 0; it < 4; ++it) {
            int o = it * 8192 + tid * 16;
            int src = o ^ (((o >> 9) & 7) << 4);
            gload_lds16(gt + src, (char*)tS + o);
        }
    }
    __syncthreads();  // drains vmcnt -> tS ready

    // phase 1: q = tS @ WqT (wave w: 64 rows x 64 cols = head w; panels w*4+nf)
    f32x4 acc[4][4];
#pragma unroll
    for (int mf = 0; mf < 4; ++mf)
#pragma unroll
        for (int nf = 0; nf < 4; ++nf) acc[mf][nf] = fz;
#pragma unroll
    for (int ks = 0; ks < 8; ++ks) {
        bf16x8 a[4];
#pragma unroll
        for (int mf = 0; mf < 4; ++mf)
            a[mf] = *(const bf16x8*)((const char*)tS + (mf * 16 + l15) * 512 + ((ks * 64 + g * 16) ^ xorm));
#pragma unroll
        for (int nf = 0; nf < 4; ++nf) {
            bf16x8 bq = *(const bf16x8*)(wqb + ((size_t)(((w * 4 + nf) * 8 + ks) * 64 + l)) * 8);
#pragma unroll
            for (int mf = 0; mf < 4; ++mf)
                acc[mf][nf] = mfma16(a[mf], bq, acc[mf][nf]);
        }
    }
    __syncthreads();  // all tS reads done before qsm overwrite

    // phase 2: softmax over head w's 64 d (this wave's 4 nf panels), -> qsm bf16
#pragma unroll
    for (int mf = 0; mf < 4; ++mf)
#pragma unroll
        for (int r = 0; r < 4; ++r) {
            float mx = -1e30f;
#pragma unroll
            for (int nf = 0; nf < 4; ++nf) mx = fmaxf(mx, acc[mf][nf][r]);
            mx = fmaxf(mx, __shfl_xor(mx, 1));
            mx = fmaxf(mx, __shfl_xor(mx, 2));
            mx = fmaxf(mx, __shfl_xor(mx, 4));
            mx = fmaxf(mx, __shfl_xor(mx, 8));
            float p[4]; float sm = 0.f;
#pragma unroll
            for (int nf = 0; nf < 4; ++nf) { p[nf] = __expf(acc[mf][nf][r] - mx); sm += p[nf]; }
            sm += __shfl_xor(sm, 1);
            sm += __shfl_xor(sm, 2);
            sm += __shfl_xor(sm, 4);
            sm += __shfl_xor(sm, 8);
            float scl = 0.125f / sm;
            int row = mf * 16 + g * 4 + r;
#pragma unroll
            for (int nf = 0; nf < 4; ++nf)
                qsm[row][w * 64 + nf * 16 + l15] = (bf16)(p[nf] * scl);
        }
    __syncthreads();

    // phase 3: out2 = qsm @ M2T (wave w: 64 rows x cols [w*32,w*32+32); panels w*2+nf)
    f32x4 acc2[4][2];
#pragma unroll
    for (int mf = 0; mf < 4; ++mf)
#pragma unroll
        for (int nf = 0; nf < 2; ++nf) acc2[mf][nf] = fz;
    const bf16* mb = m2t + (size_t)b * 131072;
#pragma unroll
    for (int ks = 0; ks < 16; ++ks) {
        bf16x8 a[4];
#pragma unroll
        for (int mf = 0; mf < 4; ++mf)
            a[mf] = *(const bf16x8*)(&qsm[mf * 16 + l15][ks * 32 + g * 8]);
#pragma unroll
        for (int nf = 0; nf < 2; ++nf) {
            bf16x8 bm = *(const bf16x8*)(mb + ((size_t)(((w * 2 + nf) * 16 + ks) * 64 + l)) * 8);
#pragma unroll
            for (int mf = 0; mf < 4; ++mf)
                acc2[mf][nf] = mfma16(a[mf], bm, acc2[mf][nf]);
        }
    }

    // phase 4: +bias, rmsnorm partials over this wave's 32 cols
#pragma unroll
    for (int nf = 0; nf < 2; ++nf) {
        float bias = cb[w * 32 + nf * 16 + l15];
#pragma unroll
        for (int mf = 0; mf < 4; ++mf)
#pragma unroll
            for (int r = 0; r < 4; ++r) acc2[mf][nf][r] += bias;
    }
#pragma unroll
    for (int mf = 0; mf < 4; ++mf)
#pragma unroll
        for (int r = 0; r < 4; ++r) {
            float ssq = 0.f;
#pragma unroll
            for (int nf = 0; nf < 2; ++nf) ssq += acc2[mf][nf][r] * acc2[mf][nf][r];
            ssq += __shfl_xor(ssq, 1);
            ssq += __shfl_xor(ssq, 2);
            ssq += __shfl_xor(ssq, 4);
            ssq += __shfl_xor(ssq, 8);
            if (l15 == 0) rowsum[w * 64 + mf * 16 + g * 4 + r] = ssq;
        }
    __syncthreads();  // rowsum complete + all phase-3 qsm reads done
    float sclr[4][4];
#pragma unroll
    for (int mf = 0; mf < 4; ++mf)
#pragma unroll
        for (int r = 0; r < 4; ++r) {
            int row = mf * 16 + g * 4 + r;
            float tot = 0.f;
#pragma unroll
            for (int ww = 0; ww < 8; ++ww) tot += rowsum[ww * 64 + row];
            sclr[mf][r] = 16.0f / fmaxf(sqrtf(tot), 1e-12f);
        }

    // epilogue: obuf[col][row] = acc2*scl*gffn + residual (re-read t; L2-hot).
    // obuf aliases qsm region (safe: barrier above covers all qsm readers);
    // rowsum region is disjoint so concurrent rowsum reads are unaffected.
    float* obuf = (float*)smem;
    const bf16* gtb = t + (size_t)(b * N_ + row0) * 256;
#pragma unroll
    for (int nf = 0; nf < 2; ++nf) {
        int col = w * 32 + nf * 16 + l15;
        float gf = gffn[col];
#pragma unroll
        for (int mf = 0; mf < 4; ++mf)
#pragma unroll
            for (int r = 0; r < 4; ++r) {
                int row = mf * 16 + g * 4 + r;
                float res = (float)gtb[row * 256 + col];
                obuf[col * 65 + row] = acc2[mf][nf][r] * sclr[mf][r] * gf + res;
            }
    }
    __syncthreads();
    // coalesced read-back: 16 lanes cover one col's 64 floats (256B), nontemporal
#pragma unroll
    for (int cc = 0; cc < 8; ++cc) {
        int c = cc * 32 + (tid >> 4);
        int j = (tid & 15) * 4;
        f32x4 v;
#pragma unroll
        for (int r = 0; r < 4; ++r) v[r] = obuf[c * 65 + j + r];
        __builtin_nontemporal_store(v, (f32x4*)(out + ((size_t)(b * 256 + c)) * N_ + row0 + j));
    }
}

extern "C" void kernel_launch(void* const* d_in, const int* in_sizes, int n_in,
                              void* d_out, int out_size, void* d_ws, size_t ws_size,
                              hipStream_t stream) {
    const float* x     = (const float*)d_in[0];
    const float* Wq    = (const float*)d_in[1];
    const float* Wk    = (const float*)d_in[2];
    const float* Wv    = (const float*)d_in[3];
    const float* cw    = (const float*)d_in[4];
    const float* cb    = (const float*)d_in[5];
    const float* gffn  = (const float*)d_in[6];
    const float* gnorm = (const float*)d_in[7];
    char* ws = (char*)d_ws;
    bf16* t    = (bf16*)(ws + T_OFF);
    float* U   = (float*)(ws + U_OFF);
    float* S   = (float*)(ws + S_OFF);
    bf16* m2t  = (bf16*)(ws + M2T_OFF);
    bf16* wqb  = (bf16*)(ws + WQ_OFF);
    bf16* wkb  = (bf16*)(ws + WK_OFF);
    bf16* wvb  = (bf16*)(ws + WV_OFF);
    float* out = (float*)d_out;

    hipMemsetAsync(U, 0, 1048576 + 16384, stream);  // U and S are contiguous
    k_nc<<<704, 256, 0, stream>>>(x, gnorm, t, Wq, Wk, Wv, wqb, wkb, wvb);
    k_kv<<<512, 256, 0, stream>>>(t, wkb, wvb, U, S);
    k_attn_m2<<<256, 256, 0, stream>>>(U, S, cw, m2t);
    k_qout<<<512, 512, 0, stream>>>(t, wqb, m2t, gffn, cb, out);
}

// Round 11
// 91.817 us; speedup vs baseline: 2.5256x; 1.0604x over previous
//
#include <hip/hip_runtime.h>
#include <hip/hip_bf16.h>

#define B_ 8
#define C_ 256
#define N_ 4096
#define HID_ 512

typedef __bf16 bf16;
typedef bf16 bf16x8 __attribute__((ext_vector_type(8)));
typedef bf16 bf16x4 __attribute__((ext_vector_type(4)));
typedef float f32x4 __attribute__((ext_vector_type(4)));

// ws layout (bytes) — round-3 footprint (20.9 MB, proven within ws_size). Do not grow.
// wqb/wkb/wvb/m2t are stored FRAGMENT-PACKED: F[p][ks][lane] = M[p*16+(lane&15)][ks*32+(lane>>4)*8+j]
// so every MFMA B-load is 64 lanes x 16B CONTIGUOUS (1 transaction vs 16 scattered).
#define T_OFF    0u           // t bf16 [B*N][256]            16 MB   (t == xn, incl. g_norm)
#define U_OFF    16777216u    // U f32  [B][8][64][64]         1 MB
#define S_OFF    17825792u    // S f32  [B][8][64]            16 KB
#define M2T_OFF  17973248u    // M2T bf16 packed [B][16p][16ks][64][8]  2 MB
#define WQ_OFF   20070400u    // Wq bf16 packed [32p][8ks][64][8]     256 KB
#define WK_OFF   20332544u
#define WV_OFF   20594688u

__device__ __forceinline__ f32x4 mfma16(bf16x8 a, bf16x8 b, f32x4 c) {
    return __builtin_amdgcn_mfma_f32_16x16x32_bf16(a, b, c, 0, 0, 0);
}

__device__ __forceinline__ void gload_lds16(const void* g, void* l) {
    __builtin_amdgcn_global_load_lds(
        (const __attribute__((address_space(1))) unsigned int*)g,
        (__attribute__((address_space(3))) unsigned int*)l, 16, 0, 0);
}

// ---- fused: rmsnorm->t (0..511) + weight cvt PACKED (512..703) + U/S zero (704..735) ----
// U/S zeroing replaces hipMemsetAsync: rocclr's fillBuffer kernel measured 41.5us
// (longest dispatch in r10!); these 32 blocks cost ~1-2us inside an existing launch.
__global__ void __launch_bounds__(256, 4) k_nc(const float* __restrict__ x,
                                               const float* __restrict__ gnorm,
                                               bf16* __restrict__ t,
                                               const float* __restrict__ wq,
                                               const float* __restrict__ wk,
                                               const float* __restrict__ wv,
                                               bf16* __restrict__ oq,
                                               bf16* __restrict__ ok,
                                               bf16* __restrict__ ov,
                                               float* __restrict__ uz) {
    if (blockIdx.x >= 704) {
        // zero U (1 MB) + S (16 KB) contiguous = 266240 floats = 66560 f32x4
        const f32x4 z = {0.f, 0.f, 0.f, 0.f};
        int idx = (blockIdx.x - 704) * 256 + threadIdx.x;
        f32x4* dst = (f32x4*)uz;
#pragma unroll
        for (int i = 0; i < 9; ++i) {
            int j = idx + i * 8192;          // 32 blocks * 256 threads
            if (j < 66560) dst[j] = z;
        }
        return;
    }
    if (blockIdx.x >= 512) {
        int bb = blockIdx.x - 512;
        int m = bb >> 6;
        const float* src = (m == 0) ? wq : ((m == 1) ? wk : wv);
        bf16* dst = (m == 0) ? oq : ((m == 1) ? ok : ov);
        int tid = threadIdx.x;
        int i0 = ((bb & 63) * 256 + tid) * 8;   // 8 consecutive k of one row
        f32x4 a = *(const f32x4*)(src + i0);
        f32x4 b2 = *(const f32x4*)(src + i0 + 4);
        bf16x8 o;
#pragma unroll
        for (int j = 0; j < 4; ++j) { o[j] = (bf16)a[j]; o[j + 4] = (bf16)b2[j]; }
        // packed dest: row=(bb&63)*8+(tid>>5), k0=(tid&31)*8
        int row = (bb & 63) * 8 + (tid >> 5);
        int k0 = (tid & 31) * 8;
        int p = row >> 4, l15 = row & 15;
        int ks = k0 >> 5, g = (k0 >> 3) & 3;
        *(bf16x8*)(dst + ((size_t)((p * 8 + ks) * 64 + g * 16 + l15)) * 8) = o;
        return;
    }
    __shared__ float part[4][64];
    int b = blockIdx.x >> 6;
    int pix = ((blockIdx.x & 63) << 6) + (threadIdx.x & 63);
    int cq = threadIdx.x >> 6;
    const float* xb = x + (size_t)b * C_ * N_ + (size_t)(cq * 64) * N_ + pix;
    float xv[64];
    float ss = 0.f;
#pragma unroll
    for (int c = 0; c < 64; ++c) { xv[c] = xb[(size_t)c * N_]; ss += xv[c] * xv[c]; }
    part[cq][threadIdx.x & 63] = ss;
    __syncthreads();
    int p = threadIdx.x & 63;
    float tot = part[0][p] + part[1][p] + part[2][p] + part[3][p];
    float s = 16.0f / fmaxf(sqrtf(tot), 1e-12f);
    bf16* tb = t + ((size_t)(b * N_ + pix)) * C_ + cq * 64;
#pragma unroll
    for (int c0 = 0; c0 < 64; c0 += 8) {
        bf16x8 pk;
#pragma unroll
        for (int j = 0; j < 8; ++j)
            pk[j] = (bf16)(xv[c0 + j] * s * gnorm[cq * 64 + c0 + j]);
        *(bf16x8*)(tb + c0) = pk;
    }
}

// ---- fused KV projection + U = exp(K)^T V , S = colsum(exp(K)) ---- (r6-proven)
// Weights read from PACKED layout: one 1KB-contiguous load per (nf,ks).
__global__ void __launch_bounds__(256, 2) k_kv(const bf16* __restrict__ t,
                                               const bf16* __restrict__ wkb,
                                               const bf16* __restrict__ wvb,
                                               float* __restrict__ U,
                                               float* __restrict__ S) {
    __shared__ __align__(16) bf16 tS[64 * 256];   // 32 KB, rows 512B, XOR-swizzled
    __shared__ __align__(16) bf16 ekT[64][72];    // stride 144B = 9*16 (b128-aligned)
    __shared__ __align__(16) bf16 vT[64][72];
    int h = blockIdx.x >> 6;
    int b = (blockIdx.x >> 3) & 7;
    int chunk = blockIdx.x & 7;
    int w = threadIdx.x >> 6;
    int l = threadIdx.x & 63;
    int l15 = l & 15, g = l >> 4;
    int xorm = (l15 & 7) << 4;

    const bf16* wsel = (w < 2) ? wkb : wvb;
    int c0 = (w & 1) * 32;
    bool isk = (w < 2);
    bf16x8 wf[2][8];
#pragma unroll
    for (int nf = 0; nf < 2; ++nf) {
        int pp = h * 4 + (w & 1) * 2 + nf;   // 16-row panel index
#pragma unroll
        for (int ks = 0; ks < 8; ++ks)
            wf[nf][ks] = *(const bf16x8*)(wsel + ((size_t)((pp * 8 + ks) * 64 + l)) * 8);
    }

    const f32x4 fz = {0.f, 0.f, 0.f, 0.f};
    f32x4 uacc[4];
#pragma unroll
    for (int df = 0; df < 4; ++df) uacc[df] = fz;
    float sreg = 0.f;

    size_t rowbase = (size_t)b * N_ + chunk * 512;
    for (int tile = 0; tile < 8; ++tile) {
        {
            const char* gt = (const char*)(t + (rowbase + tile * 64) * 256);
#pragma unroll
            for (int it = 0; it < 8; ++it) {
                int o = it * 4096 + w * 1024 + l * 16;
                int src = o ^ (((o >> 9) & 7) << 4);
                gload_lds16(gt + src, (char*)tS + it * 4096 + w * 1024);
            }
        }
        __syncthreads();  // vmcnt drained -> tS ready
        f32x4 acc[4][2];
#pragma unroll
        for (int mf = 0; mf < 4; ++mf) { acc[mf][0] = fz; acc[mf][1] = fz; }
#pragma unroll
        for (int ks = 0; ks < 8; ++ks) {
#pragma unroll
            for (int mf = 0; mf < 4; ++mf) {
                bf16x8 a = *(const bf16x8*)((const char*)tS + (mf * 16 + l15) * 512 + ((ks * 64 + g * 16) ^ xorm));
                acc[mf][0] = mfma16(a, wf[0][ks], acc[mf][0]);
                acc[mf][1] = mfma16(a, wf[1][ks], acc[mf][1]);
            }
        }
        __syncthreads();  // stage-1 tS reads + prev stage-2/S ekT/vT reads done
#pragma unroll
        for (int mf = 0; mf < 4; ++mf)
#pragma unroll
            for (int nf = 0; nf < 2; ++nf) {
                int cc = c0 + nf * 16 + l15;
                int rr = mf * 16 + g * 4;
                bf16x4 pk;
#pragma unroll
                for (int r = 0; r < 4; ++r) {
                    float v = acc[mf][nf][r];
                    pk[r] = (bf16)(isk ? __expf(v) : v);
                }
                if (isk) *(bf16x4*)(&ekT[cc][rr]) = pk;
                else     *(bf16x4*)(&vT[cc][rr]) = pk;
            }
        __syncthreads();  // ekT/vT ready
#pragma unroll
        for (int k2 = 0; k2 < 2; ++k2) {
            bf16x8 bv = *(const bf16x8*)(&vT[w * 16 + l15][k2 * 32 + g * 8]);
#pragma unroll
            for (int df = 0; df < 4; ++df) {
                bf16x8 ae = *(const bf16x8*)(&ekT[df * 16 + l15][k2 * 32 + g * 8]);
                uacc[df] = mfma16(ae, bv, uacc[df]);
            }
        }
        {
#pragma unroll
            for (int i = 0; i < 16; ++i) sreg += (float)ekT[l][w * 16 + i];
        }
    }
    int bh = b * 8 + h;
    float* Ubh = U + (size_t)bh * 4096;
#pragma unroll
    for (int df = 0; df < 4; ++df)
#pragma unroll
        for (int r = 0; r < 4; ++r)
            atomicAdd(Ubh + (df * 16 + g * 4 + r) * 64 + w * 16 + l15, uacc[df][r]);
    atomicAdd(S + bh * 64 + l, sreg);
}

// ---- attn = U/S ; M2 packed-fragment output ----
// grid 256; b = idx&7 -> same-XCD as k_qout's batch-b blocks
__global__ void __launch_bounds__(256) k_attn_m2(const float* __restrict__ U,
                                                 const float* __restrict__ S,
                                                 const float* __restrict__ cw,
                                                 bf16* __restrict__ m2t) {
    __shared__ float at[16][64];
    int b = blockIdx.x & 7, dq = (blockIdx.x >> 3) & 3, h = blockIdx.x >> 5;
    int tid = threadIdx.x;
    const float* Ub = U + (size_t)(b * 8 + h) * 4096 + dq * 16 * 64;
    const float* Sb = S + (b * 8 + h) * 64 + dq * 16;
    for (int it = 0; it < 4; ++it) {
        int idx = it * 256 + tid;  // 0..1023
        at[idx >> 6][idx & 63] = Ub[idx] / Sb[idx >> 6];
    }
    __syncthreads();
    int o = tid;
    float cwr[64];
#pragma unroll
    for (int e = 0; e < 64; ++e) cwr[e] = cw[(size_t)o * 512 + h * 64 + e];
    // packed store: M2[o][k], k = h*64 + dq*16 + j0 + j
    bf16* mb = m2t + (size_t)b * 131072;
    int pp = o >> 4, l15o = o & 15;
#pragma unroll
    for (int j0 = 0; j0 < 16; j0 += 8) {
        bf16x8 pk;
#pragma unroll
        for (int j = 0; j < 8; ++j) {
            float a2 = 0.f;
#pragma unroll
            for (int e = 0; e < 64; ++e) a2 += at[j0 + j][e] * cwr[e];
            pk[j] = (bf16)a2;
        }
        int kk = dq * 16 + j0;                 // k within head, 0..56
        int ksg = h * 2 + (kk >> 5);           // global ks (0..15)
        int gg = (kk >> 3) & 3;
        *(bf16x8*)(mb + ((size_t)((pp * 16 + ksg) * 64 + gg * 16 + l15o)) * 8) = pk;
    }
}

// ---- fused: q GEMM + per-head softmax + (qsm @ M2T) + bias + rmsnorm + residual ----
// grid 512 = b(8) x rowtile(64 of 64 rows); 512 threads (8 waves), 2 blocks/CU. (r10-proven)
__global__ void __launch_bounds__(512, 4) k_qout(const bf16* __restrict__ t,
                                                 const bf16* __restrict__ wqb,
                                                 const bf16* __restrict__ m2t,
                                                 const float* __restrict__ gffn,
                                                 const float* __restrict__ cb,
                                                 float* __restrict__ out) {
    __shared__ __align__(16) char smem[66560 + 2048];  // qsm/tS/obuf (66560) + rowsum[8][64]
    bf16 (*qsm)[520] = (bf16(*)[520])smem;
    float* rowsum = (float*)(smem + 66560);
    bf16* tS = (bf16*)smem;
    int b = blockIdx.x & 7;
    int row0 = (blockIdx.x >> 3) << 6;
    int tid = threadIdx.x;
    int w = tid >> 6, l = tid & 63;
    int l15 = l & 15, g = l >> 4;
    int xorm = (l15 & 7) << 4;
    const f32x4 fz = {0.f, 0.f, 0.f, 0.f};

    // stage t[64][256] (32KB) swizzled
    {
        const char* gt = (const char*)(t + (size_t)(b * N_ + row0) * 256);
#pragma unroll
        for (int it = 0; it < 4; ++it) {
            int o = it * 8192 + tid * 16;
            int src = o ^ (((o >> 9) & 7) << 4);
            gload_lds16(gt + src, (char*)tS + o);
        }
    }
    __syncthreads();  // drains vmcnt -> tS ready

    // phase 1: q = tS @ WqT (wave w: 64 rows x 64 cols = head w; panels w*4+nf)
    f32x4 acc[4][4];
#pragma unroll
    for (int mf = 0; mf < 4; ++mf)
#pragma unroll
        for (int nf = 0; nf < 4; ++nf) acc[mf][nf] = fz;
#pragma unroll
    for (int ks = 0; ks < 8; ++ks) {
        bf16x8 a[4];
#pragma unroll
        for (int mf = 0; mf < 4; ++mf)
            a[mf] = *(const bf16x8*)((const char*)tS + (mf * 16 + l15) * 512 + ((ks * 64 + g * 16) ^ xorm));
#pragma unroll
        for (int nf = 0; nf < 4; ++nf) {
            bf16x8 bq = *(const bf16x8*)(wqb + ((size_t)(((w * 4 + nf) * 8 + ks) * 64 + l)) * 8);
#pragma unroll
            for (int mf = 0; mf < 4; ++mf)
                acc[mf][nf] = mfma16(a[mf], bq, acc[mf][nf]);
        }
    }
    __syncthreads();  // all tS reads done before qsm overwrite

    // phase 2: softmax over head w's 64 d (this wave's 4 nf panels), -> qsm bf16
#pragma unroll
    for (int mf = 0; mf < 4; ++mf)
#pragma unroll
        for (int r = 0; r < 4; ++r) {
            float mx = -1e30f;
#pragma unroll
            for (int nf = 0; nf < 4; ++nf) mx = fmaxf(mx, acc[mf][nf][r]);
            mx = fmaxf(mx, __shfl_xor(mx, 1));
            mx = fmaxf(mx, __shfl_xor(mx, 2));
            mx = fmaxf(mx, __shfl_xor(mx, 4));
            mx = fmaxf(mx, __shfl_xor(mx, 8));
            float p[4]; float sm = 0.f;
#pragma unroll
            for (int nf = 0; nf < 4; ++nf) { p[nf] = __expf(acc[mf][nf][r] - mx); sm += p[nf]; }
            sm += __shfl_xor(sm, 1);
            sm += __shfl_xor(sm, 2);
            sm += __shfl_xor(sm, 4);
            sm += __shfl_xor(sm, 8);
            float scl = 0.125f / sm;
            int row = mf * 16 + g * 4 + r;
#pragma unroll
            for (int nf = 0; nf < 4; ++nf)
                qsm[row][w * 64 + nf * 16 + l15] = (bf16)(p[nf] * scl);
        }
    __syncthreads();

    // phase 3: out2 = qsm @ M2T (wave w: 64 rows x cols [w*32,w*32+32); panels w*2+nf)
    f32x4 acc2[4][2];
#pragma unroll
    for (int mf = 0; mf < 4; ++mf)
#pragma unroll
        for (int nf = 0; nf < 2; ++nf) acc2[mf][nf] = fz;
    const bf16* mb = m2t + (size_t)b * 131072;
#pragma unroll
    for (int ks = 0; ks < 16; ++ks) {
        bf16x8 a[4];
#pragma unroll
        for (int mf = 0; mf < 4; ++mf)
            a[mf] = *(const bf16x8*)(&qsm[mf * 16 + l15][ks * 32 + g * 8]);
#pragma unroll
        for (int nf = 0; nf < 2; ++nf) {
            bf16x8 bm = *(const bf16x8*)(mb + ((size_t)(((w * 2 + nf) * 16 + ks) * 64 + l)) * 8);
#pragma unroll
            for (int mf = 0; mf < 4; ++mf)
                acc2[mf][nf] = mfma16(a[mf], bm, acc2[mf][nf]);
        }
    }

    // phase 4: +bias, rmsnorm partials over this wave's 32 cols
#pragma unroll
    for (int nf = 0; nf < 2; ++nf) {
        float bias = cb[w * 32 + nf * 16 + l15];
#pragma unroll
        for (int mf = 0; mf < 4; ++mf)
#pragma unroll
            for (int r = 0; r < 4; ++r) acc2[mf][nf][r] += bias;
    }
#pragma unroll
    for (int mf = 0; mf < 4; ++mf)
#pragma unroll
        for (int r = 0; r < 4; ++r) {
            float ssq = 0.f;
#pragma unroll
            for (int nf = 0; nf < 2; ++nf) ssq += acc2[mf][nf][r] * acc2[mf][nf][r];
            ssq += __shfl_xor(ssq, 1);
            ssq += __shfl_xor(ssq, 2);
            ssq += __shfl_xor(ssq, 4);
            ssq += __shfl_xor(ssq, 8);
            if (l15 == 0) rowsum[w * 64 + mf * 16 + g * 4 + r] = ssq;
        }
    __syncthreads();  // rowsum complete + all phase-3 qsm reads done
    float sclr[4][4];
#pragma unroll
    for (int mf = 0; mf < 4; ++mf)
#pragma unroll
        for (int r = 0; r < 4; ++r) {
            int row = mf * 16 + g * 4 + r;
            float tot = 0.f;
#pragma unroll
            for (int ww = 0; ww < 8; ++ww) tot += rowsum[ww * 64 + row];
            sclr[mf][r] = 16.0f / fmaxf(sqrtf(tot), 1e-12f);
        }

    // epilogue: obuf[col][row] = acc2*scl*gffn + residual (re-read t; L2-hot).
    float* obuf = (float*)smem;
    const bf16* gtb = t + (size_t)(b * N_ + row0) * 256;
#pragma unroll
    for (int nf = 0; nf < 2; ++nf) {
        int col = w * 32 + nf * 16 + l15;
        float gf = gffn[col];
#pragma unroll
        for (int mf = 0; mf < 4; ++mf)
#pragma unroll
            for (int r = 0; r < 4; ++r) {
                int row = mf * 16 + g * 4 + r;
                float res = (float)gtb[row * 256 + col];
                obuf[col * 65 + row] = acc2[mf][nf][r] * sclr[mf][r] * gf + res;
            }
    }
    __syncthreads();
    // coalesced read-back: 16 lanes cover one col's 64 floats (256B), nontemporal
#pragma unroll
    for (int cc = 0; cc < 8; ++cc) {
        int c = cc * 32 + (tid >> 4);
        int j = (tid & 15) * 4;
        f32x4 v;
#pragma unroll
        for (int r = 0; r < 4; ++r) v[r] = obuf[c * 65 + j + r];
        __builtin_nontemporal_store(v, (f32x4*)(out + ((size_t)(b * 256 + c)) * N_ + row0 + j));
    }
}

extern "C" void kernel_launch(void* const* d_in, const int* in_sizes, int n_in,
                              void* d_out, int out_size, void* d_ws, size_t ws_size,
                              hipStream_t stream) {
    const float* x     = (const float*)d_in[0];
    const float* Wq    = (const float*)d_in[1];
    const float* Wk    = (const float*)d_in[2];
    const float* Wv    = (const float*)d_in[3];
    const float* cw    = (const float*)d_in[4];
    const float* cb    = (const float*)d_in[5];
    const float* gffn  = (const float*)d_in[6];
    const float* gnorm = (const float*)d_in[7];
    char* ws = (char*)d_ws;
    bf16* t    = (bf16*)(ws + T_OFF);
    float* U   = (float*)(ws + U_OFF);
    float* S   = (float*)(ws + S_OFF);
    bf16* m2t  = (bf16*)(ws + M2T_OFF);
    bf16* wqb  = (bf16*)(ws + WQ_OFF);
    bf16* wkb  = (bf16*)(ws + WK_OFF);
    bf16* wvb  = (bf16*)(ws + WV_OFF);
    float* out = (float*)d_out;

    k_nc<<<736, 256, 0, stream>>>(x, gnorm, t, Wq, Wk, Wv, wqb, wkb, wvb, U);
    k_kv<<<512, 256, 0, stream>>>(t, wkb, wvb, U, S);
    k_attn_m2<<<256, 256, 0, stream>>>(U, S, cw, m2t);
    k_qout<<<512, 512, 0, stream>>>(t, wqb, m2t, gffn, cb, out);
}